// Round 5
// baseline (683.795 us; speedup 1.0000x reference)
//
#include <hip/hip_runtime.h>

// Paired CGCNN (separated) — R4.
// R4: hoist all fp32->bf16 conversion out of the hot conv kernel.
//  - k_w3cvt: 6x W3 -> bf16 W3^T (128 x 64, zero-padded) once per call.
//  - k_nbrcvt: nbr_fea -> bf16 rows padded to 72 (144B stride) once per branch,
//    reused by 3 conv layers (buffer shared across branches).
//  - k_convfused: A-stage is a pure 16B-chunk copy; B-frags load directly
//    global->VGPR from bf16 W3^T. MFMA/spill/epilogue unchanged from R3.
//  - k_y12: k_embed-style (thread=(atom,col), uniform s_load a-row, coalesced W).

constexpr int NATOM = 20000;
constexpr int MNBR  = 12;
constexpr int ORIG  = 92;
constexpr int NBRF  = 41;
constexpr int F     = 64;
constexpr int H     = 128;
constexpr int NCONV = 3;
constexpr int NCRYS = 400;

#define DEVFN __device__ __forceinline__

typedef __attribute__((ext_vector_type(8))) short short8;   // 8 bf16 (4 VGPR)
typedef __attribute__((ext_vector_type(4))) float f32x4;    // MFMA acc

DEVFN float softplusf(float x) {
    return fmaxf(x, 0.f) + __logf(1.f + __expf(-fabsf(x)));
}
DEVFN float sigmoidf(float x) {
    return __builtin_amdgcn_rcpf(1.f + __expf(-x));
}
DEVFN unsigned short f2bf(float x) {  // RNE fp32->bf16
    union { float f; unsigned u; } v{x};
    unsigned r = v.u + 0x7FFF + ((v.u >> 16) & 1);
    return (unsigned short)(r >> 16);
}

template <typename T>
DEVFN const T* upt(const T* p) {
    unsigned long long v = (unsigned long long)p;
    unsigned lo = __builtin_amdgcn_readfirstlane((unsigned)v);
    unsigned hi = __builtin_amdgcn_readfirstlane((unsigned)(v >> 32));
    return (const T*)((((unsigned long long)hi) << 32) | lo);
}

// ---------------- w3cvt: 6 x (41,128) fp32 -> (128,64) bf16 col-major-K ----------------
__global__ __launch_bounds__(256) void k_w3cvt(const float* __restrict__ convW_A,
                                               const float* __restrict__ convW_B,
                                               unsigned* __restrict__ w3t) {  // as uint pairs
#pragma unroll
    for (int it = 0; it < 4; ++it) {
        int e = it * 6144 + blockIdx.x * 256 + threadIdx.x;  // 0..24575
        int mat = e >> 12;           // 6 mats x 4096 uints
        int rem = e & 4095;
        int col = rem >> 5, kp = rem & 31, k = kp * 2;
        int br = mat / 3, l = mat - br * 3;
        const float* src = (br ? convW_B : convW_A) + (size_t)l * (2 * F + NBRF) * H + 128 * H;
        float v0 = (k < NBRF) ? src[k * H + col] : 0.f;
        float v1 = (k + 1 < NBRF) ? src[(k + 1) * H + col] : 0.f;
        w3t[e] = (unsigned)f2bf(v0) | ((unsigned)f2bf(v1) << 16);
    }
}

// ---------------- nbrcvt: (N*12,41) fp32 -> (N*12,72) bf16 (zeros past 41) ----------------
__global__ __launch_bounds__(256) void k_nbrcvt(const float* __restrict__ nbr,
                                                unsigned* __restrict__ out) {  // uint pairs
    int e = blockIdx.x * 256 + threadIdx.x;  // 0 .. 240000*36-1
    int row = e / 36;
    int kp = e - row * 36, k = kp * 2;
    const float* s = nbr + (size_t)row * NBRF;
    float v0 = (k < NBRF) ? s[k] : 0.f;
    float v1 = (k + 1 < NBRF) ? s[k + 1] : 0.f;
    out[(size_t)row * 36 + kp] = (unsigned)f2bf(v0) | ((unsigned)f2bf(v1) << 16);
}

// ---------------- embed ----------------
__global__ __launch_bounds__(256) void k_embed(const float* __restrict__ atom,
                                               const float* __restrict__ W,
                                               const float* __restrict__ b,
                                               float* __restrict__ out) {
    __shared__ float sW[ORIG * F];
    for (int i = threadIdx.x; i < ORIG * F; i += 256) sW[i] = W[i];
    __syncthreads();
    int n = blockIdx.x * 4 + (threadIdx.x >> 6);
    int f = threadIdx.x & 63;
    const float* ar = upt(atom + n * ORIG);
    float acc = b[f];
#pragma unroll
    for (int k = 0; k < ORIG; ++k) acc += ar[k] * sW[k * F + f];
    out[n * F + f] = acc;
}

// ---------------- y12 v2: thread=(atom,col); uniform a-row, coalesced W ----------------
__global__ __launch_bounds__(256) void k_y12(const float* __restrict__ a,
                                             const float* __restrict__ W,  // (169,128)
                                             float* __restrict__ y1,
                                             float* __restrict__ y2) {
    int t = threadIdx.x;
    int al = t >> 7;           // 0..1 (wave-uniform)
    int col = t & 127;
    int atom = blockIdx.x * 2 + al;
    const float* ar = upt(a + atom * F);
    const float* w1 = W + col;           // rows 0..63
    const float* w2 = W + 64 * H + col;  // rows 64..127
    float acc1 = 0.f, acc2 = 0.f;
#pragma unroll
    for (int k = 0; k < F; ++k) {
        float av = ar[k];
        acc1 = fmaf(av, w1[k * H], acc1);
        acc2 = fmaf(av, w2[k * H], acc2);
    }
    y1[atom * H + col] = acc1;
    y2[atom * H + col] = acc2;
}

// ---------------- fused conv layer: MFMA z-tile + epilogue reduce ----------------
// Block = 4 atoms = 48 nbr-rows. LDS pool (27072 B):
//   [0,     6912)  sA  : 48 rows x 72 bf16 (pre-converted, stride 144B)
//   [0,    25344)  sZ  : 48 x 132 f32 (aliases sA after MFMA phase)
//   [25344,26880)  BN  : sS1[128] sH1[128] sS2[64] sH2[64]
//   [26880,27072)  sJ  : 48 neighbor indices
__global__ __launch_bounds__(256, 4) void k_convfused(
        const float* __restrict__ y1,
        const float* __restrict__ y2,
        const unsigned short* __restrict__ nbrb,  // (N*12, 72) bf16
        const int* __restrict__ idx,              // (N,12)
        const unsigned short* __restrict__ w3l,   // (128, 64) bf16 W3^T this layer
        const float* __restrict__ bias,           // (128)
        const float* __restrict__ bn1,            // (4,128)
        const float* __restrict__ bn2,            // (4,64)
        float* __restrict__ a) {
    __shared__ __align__(16) unsigned char pool[27072];
    float* sZ  = (float*)pool;
    float* sS1 = (float*)(pool + 25344);
    float* sH1 = sS1 + 128;
    float* sS2 = sH1 + 128;
    float* sH2 = sS2 + 64;
    int*   sJ  = (int*)(pool + 26880);

    int t = threadIdx.x;
    int atom0 = blockIdx.x * 4;
    int R0 = atom0 * MNBR;  // 48 rows

    // --- stage A: pure copy, 432 x 16B chunks (9 per row) ---
#pragma unroll
    for (int j = 0; j < 2; ++j) {
        int c = t + j * 256;
        if (c < 432) {
            int row = c / 9, sub = c - row * 9;
            short8 v = *(const short8*)(nbrb + (size_t)(R0 + row) * 72 + sub * 8);
            *(short8*)(pool + row * 144 + sub * 16) = v;
        }
    }
    // --- BN fold + neighbor indices ---
    if (t < 128) {
        float g = bn1[t], be = bn1[128 + t], mu = bn1[256 + t], va = bn1[384 + t];
        float s = g * rsqrtf(va + 1e-5f);
        sS1[t] = s;
        sH1[t] = be - mu * s + bias[t] * s;
    } else if (t < 192) {
        int u = t - 128;
        float g = bn2[u], be = bn2[64 + u], mu = bn2[128 + u], va = bn2[192 + u];
        float s = g * rsqrtf(va + 1e-5f);
        sS2[u] = s;
        sH2[u] = be - mu * s;
    }
    if (t < 48) sJ[t] = idx[R0 + t];

    // --- B-frags: direct global->VGPR (L2-hot bf16 W3^T) ---
    int w = t >> 6, lane = t & 63;
    int lr = lane & 15, lq = lane >> 4;
    int CB = w * 32;
    short8 bfr[2][2];  // [kstep][n]
#pragma unroll
    for (int kstep = 0; kstep < 2; ++kstep)
#pragma unroll
        for (int n = 0; n < 2; ++n) {
            int col = CB + n * 16 + lr;
            int ks = kstep * 32 + lq * 8;
            bfr[kstep][n] = *(const short8*)(w3l + (size_t)col * 64 + ks);
        }
    __syncthreads();

    // --- MFMA: 3 row-frags x 2 col-frags x 2 k-steps ---
    f32x4 acc[2][3];
#pragma unroll
    for (int n = 0; n < 2; ++n)
#pragma unroll
        for (int r = 0; r < 3; ++r) acc[n][r] = f32x4{0.f, 0.f, 0.f, 0.f};

#pragma unroll
    for (int kstep = 0; kstep < 2; ++kstep) {
        int ks = kstep * 32 + lq * 8;
        short8 af[3];
#pragma unroll
        for (int r = 0; r < 3; ++r) {
            int row = r * 16 + lr;
            af[r] = *(const short8*)(pool + (size_t)row * 144 + ks * 2);
        }
#pragma unroll
        for (int n = 0; n < 2; ++n)
#pragma unroll
            for (int r = 0; r < 3; ++r)
                acc[n][r] = __builtin_amdgcn_mfma_f32_16x16x32_bf16(af[r], bfr[kstep][n], acc[n][r], 0, 0, 0);
    }
    __syncthreads();  // sA reads done -> safe to overwrite with sZ

    // --- spill z-tile: D layout col=lane&15, row=(lane>>4)*4+reg ---
#pragma unroll
    for (int n = 0; n < 2; ++n)
#pragma unroll
        for (int r = 0; r < 3; ++r)
#pragma unroll
            for (int q = 0; q < 4; ++q) {
                int row = r * 16 + lq * 4 + q;
                int col = CB + n * 16 + lr;
                sZ[row * 132 + col] = acc[n][r][q];
            }
    __syncthreads();

    // --- epilogue: thread = (atom, feature); reduce 12 neighbors ---
    int al = t >> 6, f = t & 63;
    int i = atom0 + al;
    float y1f = y1[i * H + f], y1c = y1[i * H + 64 + f];
    float s1f = sS1[f], h1f = sH1[f], s1c = sS1[64 + f], h1c = sH1[64 + f];

    int js[MNBR];
#pragma unroll
    for (int m = 0; m < MNBR; ++m) js[m] = sJ[al * MNBR + m];
    float gf[MNBR], gc[MNBR];
#pragma unroll
    for (int m = 0; m < MNBR; ++m) {
        gf[m] = y2[js[m] * H + f];
        gc[m] = y2[js[m] * H + 64 + f];
    }

    float sacc = 0.f;
#pragma unroll
    for (int m = 0; m < MNBR; ++m) {
        int row = al * MNBR + m;
        float zf = sZ[row * 132 + f] + y1f + gf[m];
        float zc = sZ[row * 132 + 64 + f] + y1c + gc[m];
        zf = zf * s1f + h1f;
        zc = zc * s1c + h1c;
        sacc += sigmoidf(zf) * softplusf(zc);
    }
    float av = a[i * F + f];
    a[i * F + f] = softplusf(av + sacc * sS2[f] + sH2[f]);
}

// ---------------- pool ----------------
__global__ __launch_bounds__(256) void k_pool(const float* __restrict__ a,
                                              const int* __restrict__ seg,
                                              float* __restrict__ pool,
                                              float* __restrict__ cnt) {
    int idx = blockIdx.x * 256 + threadIdx.x;
    int n = idx >> 6, f = idx & 63;
    int c = seg[n];
    atomicAdd(&pool[c * F + f], a[idx]);
    if (f == 0) atomicAdd(&cnt[c], 1.f);
}

// ---------------- dense ----------------
__global__ __launch_bounds__(128) void k_dense(const float* __restrict__ pool,
                                               const float* __restrict__ cnt,
                                               const float* __restrict__ W,
                                               const float* __restrict__ b,
                                               float* __restrict__ crys) {
    int c = blockIdx.x;
    int h = threadIdx.x;
    __shared__ float sp[F];
    if (h < F) sp[h] = pool[c * F + h] / fmaxf(cnt[c], 1.f);
    __syncthreads();
    float acc = b[h];
#pragma unroll
    for (int k = 0; k < F; ++k) acc += sp[k] * W[k * H + h];
    crys[c * H + h] = softplusf(acc);
}

// ---------------- combine ----------------
__global__ __launch_bounds__(128) void k_combine(const float* __restrict__ cA,
                                                 const float* __restrict__ cB,
                                                 const float* __restrict__ ffW,
                                                 const float* __restrict__ ffb,
                                                 const float* __restrict__ outW,
                                                 const float* __restrict__ outb,
                                                 float* __restrict__ out) {
    int c = blockIdx.x;
    int h = threadIdx.x;
    __shared__ float sd[H];
    __shared__ float st[H];
    sd[h] = fabsf(cA[c * H + h] - cB[c * H + h]);
    __syncthreads();
    float acc = ffb[h];
#pragma unroll
    for (int k = 0; k < H; ++k) acc += sd[k] * ffW[k * H + h];
    st[h] = softplusf(acc) * outW[h];
    __syncthreads();
    for (int s = 64; s > 0; s >>= 1) {
        if (h < s) st[h] += st[h + s];
        __syncthreads();
    }
    if (h == 0) out[c] = st[0] + outb[0];
}

extern "C" void kernel_launch(void* const* d_in, const int* in_sizes, int n_in,
                              void* d_out, int out_size, void* d_ws, size_t ws_size,
                              hipStream_t stream) {
    const float* ffW  = (const float*)d_in[24];
    const float* ffb  = (const float*)d_in[25];
    const float* outW = (const float*)d_in[26];
    const float* outb = (const float*)d_in[27];

    float* ws = (float*)d_ws;
    float* aA    = ws;                        // N*F
    float* aB    = aA + NATOM * F;
    float* y1    = aB + NATOM * F;            // N*H
    float* y2    = y1 + NATOM * H;
    float* poolA = y2 + NATOM * H;
    float* poolB = poolA + NCRYS * F;
    float* cntA  = poolB + NCRYS * F;
    float* cntB  = cntA + NCRYS;
    float* crA   = cntB + NCRYS;
    float* crB   = crA + NCRYS * H;
    unsigned* w3t  = (unsigned*)(crB + NCRYS * H);          // 24576 uints
    unsigned* nbrb = w3t + 24576;                           // N*12*36 uints (shared A/B)

    hipMemsetAsync(poolA, 0, (size_t)(2 * NCRYS * F + 2 * NCRYS) * sizeof(float), stream);

    const float* convW_A = (const float*)d_in[6];
    const float* convW_B = (const float*)d_in[18];
    k_w3cvt<<<24, 256, 0, stream>>>(convW_A, convW_B, w3t);

    for (int br = 0; br < 2; ++br) {
        int o = br * 12;
        const float* atom  = (const float*)d_in[o + 0];
        const float* nbrf  = (const float*)d_in[o + 1];
        const int*   nidx  = (const int*)d_in[o + 2];
        const int*   seg   = (const int*)d_in[o + 3];
        const float* embW  = (const float*)d_in[o + 4];
        const float* embb  = (const float*)d_in[o + 5];
        const float* convb = (const float*)d_in[o + 7];
        const float* bn1   = (const float*)d_in[o + 8];
        const float* bn2   = (const float*)d_in[o + 9];
        const float* denW  = (const float*)d_in[o + 10];
        const float* denb  = (const float*)d_in[o + 11];

        float* a    = br ? aB : aA;
        float* pool = br ? poolB : poolA;
        float* cnt  = br ? cntB : cntA;
        float* cr   = br ? crB : crA;

        k_nbrcvt<<<NATOM * MNBR * 36 / 256, 256, 0, stream>>>(nbrf, nbrb);
        k_embed<<<NATOM / 4, 256, 0, stream>>>(atom, embW, embb, a);
        for (int l = 0; l < NCONV; ++l) {
            const unsigned short* w3l = (const unsigned short*)(w3t + (size_t)(br * 3 + l) * 4096);
            k_y12<<<NATOM / 2, 256, 0, stream>>>(a, (br ? convW_B : convW_A) + (size_t)l * (2 * F + NBRF) * H, y1, y2);
            k_convfused<<<NATOM / 4, 256, 0, stream>>>(y1, y2, (const unsigned short*)nbrb, nidx,
                                                       w3l,
                                                       convb + l * H,
                                                       bn1 + l * 4 * H,
                                                       bn2 + l * 4 * F,
                                                       a);
        }
        k_pool<<<NATOM * F / 256, 256, 0, stream>>>(a, seg, pool, cnt);
        k_dense<<<NCRYS, 128, 0, stream>>>(pool, cnt, denW, denb, cr);
    }

    k_combine<<<NCRYS, 128, 0, stream>>>(crA, crB, ffW, ffb, outW, outb, (float*)d_out);
}

// Round 6
// 415.630 us; speedup vs baseline: 1.6452x; 1.6452x over previous
//
#include <hip/hip_runtime.h>

// Paired CGCNN (separated) — R5.
// R5: y12 becomes an MFMA GEMM (32 atoms/block, 4 waves x 64 cols) with a
// hi/lo bf16 split (Ah*Wh + Ah*Wl + Al*Wh ~ fp32 accuracy). a_hi/a_lo are
// written by embed/convfused epilogues; W12^T hi/lo precomputed in k_wcvt.
// convfused unchanged from R4 (validated). `a` buffer shared across branches.

constexpr int NATOM = 20000;
constexpr int MNBR  = 12;
constexpr int ORIG  = 92;
constexpr int NBRF  = 41;
constexpr int F     = 64;
constexpr int H     = 128;
constexpr int NCONV = 3;
constexpr int NCRYS = 400;

#define DEVFN __device__ __forceinline__

typedef __attribute__((ext_vector_type(8))) short short8;   // 8 bf16 (4 VGPR)
typedef __attribute__((ext_vector_type(4))) float f32x4;    // MFMA acc

DEVFN float softplusf(float x) {
    return fmaxf(x, 0.f) + __logf(1.f + __expf(-fabsf(x)));
}
DEVFN float sigmoidf(float x) {
    return __builtin_amdgcn_rcpf(1.f + __expf(-x));
}
DEVFN unsigned short f2bf(float x) {  // RNE fp32->bf16
    union { float f; unsigned u; } v{x};
    unsigned r = v.u + 0x7FFF + ((v.u >> 16) & 1);
    return (unsigned short)(r >> 16);
}
DEVFN float bf2f(unsigned short h) {
    union { unsigned u; float f; } v;
    v.u = (unsigned)h << 16;
    return v.f;
}

template <typename T>
DEVFN const T* upt(const T* p) {
    unsigned long long v = (unsigned long long)p;
    unsigned lo = __builtin_amdgcn_readfirstlane((unsigned)v);
    unsigned hi = __builtin_amdgcn_readfirstlane((unsigned)(v >> 32));
    return (const T*)((((unsigned long long)hi) << 32) | lo);
}

// ---------------- wcvt: W3^T bf16 (6x128x64) + W12^T hi/lo bf16 (6x256x64) ----------------
__global__ __launch_bounds__(256) void k_wcvt(const float* __restrict__ convW_A,
                                              const float* __restrict__ convW_B,
                                              unsigned* __restrict__ w3t,
                                              unsigned* __restrict__ w12h,
                                              unsigned* __restrict__ w12l) {
    int e = blockIdx.x * 256 + threadIdx.x;  // 0..73727
    if (e < 24576) {
        int mat = e >> 12;
        int rem = e & 4095;
        int col = rem >> 5, kp = rem & 31, k = kp * 2;
        int br = mat / 3, l = mat - br * 3;
        const float* src = (br ? convW_B : convW_A) + (size_t)l * (2 * F + NBRF) * H + 128 * H;
        float v0 = (k < NBRF) ? src[k * H + col] : 0.f;
        float v1 = (k + 1 < NBRF) ? src[(k + 1) * H + col] : 0.f;
        w3t[e] = (unsigned)f2bf(v0) | ((unsigned)f2bf(v1) << 16);
    } else {
        int e2 = e - 24576;              // < 49152
        int mat = e2 >> 13;              // 6 mats x 8192 uints
        int rem = e2 & 8191;
        int col = rem >> 5, kp = rem & 31, k = kp * 2;
        const float* src = (mat >= 3 ? convW_B : convW_A) + (size_t)(mat % 3) * (2 * F + NBRF) * H;
        float v0, v1;
        if (col < 128) { v0 = src[k * H + col];            v1 = src[(k + 1) * H + col]; }
        else           { v0 = src[(64 + k) * H + col - 128]; v1 = src[(64 + k + 1) * H + col - 128]; }
        unsigned short h0 = f2bf(v0), h1 = f2bf(v1);
        w12h[e2] = (unsigned)h0 | ((unsigned)h1 << 16);
        w12l[e2] = (unsigned)f2bf(v0 - bf2f(h0)) | ((unsigned)f2bf(v1 - bf2f(h1)) << 16);
    }
}

// ---------------- nbrcvt: (N*12,41) fp32 -> (N*12,72) bf16 (zeros past 41) ----------------
__global__ __launch_bounds__(256) void k_nbrcvt(const float* __restrict__ nbr,
                                                unsigned* __restrict__ out) {
    int e = blockIdx.x * 256 + threadIdx.x;
    int row = e / 36;
    int kp = e - row * 36, k = kp * 2;
    const float* s = nbr + (size_t)row * NBRF;
    float v0 = (k < NBRF) ? s[k] : 0.f;
    float v1 = (k + 1 < NBRF) ? s[k + 1] : 0.f;
    out[(size_t)row * 36 + kp] = (unsigned)f2bf(v0) | ((unsigned)f2bf(v1) << 16);
}

// ---------------- embed: writes a fp32 + hi/lo bf16 ----------------
__global__ __launch_bounds__(256) void k_embed(const float* __restrict__ atom,
                                               const float* __restrict__ W,
                                               const float* __restrict__ b,
                                               float* __restrict__ out,
                                               unsigned short* __restrict__ aHi,
                                               unsigned short* __restrict__ aLo) {
    __shared__ float sW[ORIG * F];
    for (int i = threadIdx.x; i < ORIG * F; i += 256) sW[i] = W[i];
    __syncthreads();
    int n = blockIdx.x * 4 + (threadIdx.x >> 6);
    int f = threadIdx.x & 63;
    const float* ar = upt(atom + n * ORIG);
    float acc = b[f];
#pragma unroll
    for (int k = 0; k < ORIG; ++k) acc += ar[k] * sW[k * F + f];
    out[n * F + f] = acc;
    unsigned short h = f2bf(acc);
    aHi[n * F + f] = h;
    aLo[n * F + f] = f2bf(acc - bf2f(h));
}

// ---------------- y12 (MFMA, hi/lo split): (32 atoms)x(256 cols) per block ----------------
__global__ __launch_bounds__(256, 2) void k_y12(const unsigned short* __restrict__ aHi,
                                                const unsigned short* __restrict__ aLo,
                                                const unsigned short* __restrict__ w12h,  // (256,64) this layer
                                                const unsigned short* __restrict__ w12l,
                                                float* __restrict__ y1,
                                                float* __restrict__ y2) {
    __shared__ __align__(16) unsigned short sH[32 * 72];
    __shared__ __align__(16) unsigned short sL[32 * 72];
    int t = threadIdx.x;
    int atom0 = blockIdx.x * 32;
    {
        int row = t >> 3, sub = t & 7;
        *(short8*)(sH + row * 72 + sub * 8) = *(const short8*)(aHi + (size_t)(atom0 + row) * 64 + sub * 8);
        *(short8*)(sL + row * 72 + sub * 8) = *(const short8*)(aLo + (size_t)(atom0 + row) * 64 + sub * 8);
    }
    int w = t >> 6, lane = t & 63;
    int lr = lane & 15, lq = lane >> 4;

    short8 bh[2][4], bl[2][4];
#pragma unroll
    for (int kstep = 0; kstep < 2; ++kstep)
#pragma unroll
        for (int n = 0; n < 4; ++n) {
            int col = w * 64 + n * 16 + lr;
            size_t off = (size_t)col * 64 + kstep * 32 + lq * 8;
            bh[kstep][n] = *(const short8*)(w12h + off);
            bl[kstep][n] = *(const short8*)(w12l + off);
        }
    __syncthreads();

    f32x4 acc[4][2];
#pragma unroll
    for (int n = 0; n < 4; ++n)
#pragma unroll
        for (int r = 0; r < 2; ++r) acc[n][r] = f32x4{0.f, 0.f, 0.f, 0.f};

#pragma unroll
    for (int kstep = 0; kstep < 2; ++kstep) {
        int ks = kstep * 32 + lq * 8;
        short8 ah[2], al[2];
#pragma unroll
        for (int r = 0; r < 2; ++r) {
            ah[r] = *(const short8*)(sH + (r * 16 + lr) * 72 + ks);
            al[r] = *(const short8*)(sL + (r * 16 + lr) * 72 + ks);
        }
#pragma unroll
        for (int n = 0; n < 4; ++n)
#pragma unroll
            for (int r = 0; r < 2; ++r) {
                acc[n][r] = __builtin_amdgcn_mfma_f32_16x16x32_bf16(ah[r], bh[kstep][n], acc[n][r], 0, 0, 0);
                acc[n][r] = __builtin_amdgcn_mfma_f32_16x16x32_bf16(ah[r], bl[kstep][n], acc[n][r], 0, 0, 0);
                acc[n][r] = __builtin_amdgcn_mfma_f32_16x16x32_bf16(al[r], bh[kstep][n], acc[n][r], 0, 0, 0);
            }
    }

    // D layout: col=lane&15, row=(lane>>4)*4+q
#pragma unroll
    for (int n = 0; n < 4; ++n) {
        int col = w * 64 + n * 16 + lr;
        float* dst = (col < 128) ? (y1 + col) : (y2 + col - 128);
#pragma unroll
        for (int r = 0; r < 2; ++r)
#pragma unroll
            for (int q = 0; q < 4; ++q) {
                int atom = atom0 + r * 16 + lq * 4 + q;
                dst[(size_t)atom * H] = acc[n][r][q];
            }
    }
}

// ---------------- fused conv layer: MFMA z-tile + epilogue reduce ----------------
__global__ __launch_bounds__(256, 4) void k_convfused(
        const float* __restrict__ y1,
        const float* __restrict__ y2,
        const unsigned short* __restrict__ nbrb,  // (N*12, 72) bf16
        const int* __restrict__ idx,              // (N,12)
        const unsigned short* __restrict__ w3l,   // (128, 64) bf16 W3^T this layer
        const float* __restrict__ bias,
        const float* __restrict__ bn1,
        const float* __restrict__ bn2,
        float* __restrict__ a,
        unsigned short* __restrict__ aHi,
        unsigned short* __restrict__ aLo) {
    __shared__ __align__(16) unsigned char pool[27072];
    float* sZ  = (float*)pool;
    float* sS1 = (float*)(pool + 25344);
    float* sH1 = sS1 + 128;
    float* sS2 = sH1 + 128;
    float* sH2 = sS2 + 64;
    int*   sJ  = (int*)(pool + 26880);

    int t = threadIdx.x;
    int atom0 = blockIdx.x * 4;
    int R0 = atom0 * MNBR;

    // stage A: pure copy, 432 x 16B chunks
#pragma unroll
    for (int j = 0; j < 2; ++j) {
        int c = t + j * 256;
        if (c < 432) {
            int row = c / 9, sub = c - row * 9;
            short8 v = *(const short8*)(nbrb + (size_t)(R0 + row) * 72 + sub * 8);
            *(short8*)(pool + row * 144 + sub * 16) = v;
        }
    }
    if (t < 128) {
        float g = bn1[t], be = bn1[128 + t], mu = bn1[256 + t], va = bn1[384 + t];
        float s = g * rsqrtf(va + 1e-5f);
        sS1[t] = s;
        sH1[t] = be - mu * s + bias[t] * s;
    } else if (t < 192) {
        int u = t - 128;
        float g = bn2[u], be = bn2[64 + u], mu = bn2[128 + u], va = bn2[192 + u];
        float s = g * rsqrtf(va + 1e-5f);
        sS2[u] = s;
        sH2[u] = be - mu * s;
    }
    if (t < 48) sJ[t] = idx[R0 + t];

    int w = t >> 6, lane = t & 63;
    int lr = lane & 15, lq = lane >> 4;
    int CB = w * 32;
    short8 bfr[2][2];
#pragma unroll
    for (int kstep = 0; kstep < 2; ++kstep)
#pragma unroll
        for (int n = 0; n < 2; ++n) {
            int col = CB + n * 16 + lr;
            int ks = kstep * 32 + lq * 8;
            bfr[kstep][n] = *(const short8*)(w3l + (size_t)col * 64 + ks);
        }
    __syncthreads();

    f32x4 acc[2][3];
#pragma unroll
    for (int n = 0; n < 2; ++n)
#pragma unroll
        for (int r = 0; r < 3; ++r) acc[n][r] = f32x4{0.f, 0.f, 0.f, 0.f};

#pragma unroll
    for (int kstep = 0; kstep < 2; ++kstep) {
        int ks = kstep * 32 + lq * 8;
        short8 af[3];
#pragma unroll
        for (int r = 0; r < 3; ++r) {
            int row = r * 16 + lr;
            af[r] = *(const short8*)(pool + (size_t)row * 144 + ks * 2);
        }
#pragma unroll
        for (int n = 0; n < 2; ++n)
#pragma unroll
            for (int r = 0; r < 3; ++r)
                acc[n][r] = __builtin_amdgcn_mfma_f32_16x16x32_bf16(af[r], bfr[kstep][n], acc[n][r], 0, 0, 0);
    }
    __syncthreads();

#pragma unroll
    for (int n = 0; n < 2; ++n)
#pragma unroll
        for (int r = 0; r < 3; ++r)
#pragma unroll
            for (int q = 0; q < 4; ++q) {
                int row = r * 16 + lq * 4 + q;
                int col = CB + n * 16 + lr;
                sZ[row * 132 + col] = acc[n][r][q];
            }
    __syncthreads();

    int al = t >> 6, f = t & 63;
    int i = atom0 + al;
    float y1f = y1[i * H + f], y1c = y1[i * H + 64 + f];
    float s1f = sS1[f], h1f = sH1[f], s1c = sS1[64 + f], h1c = sH1[64 + f];

    int js[MNBR];
#pragma unroll
    for (int m = 0; m < MNBR; ++m) js[m] = sJ[al * MNBR + m];
    float gf[MNBR], gc[MNBR];
#pragma unroll
    for (int m = 0; m < MNBR; ++m) {
        gf[m] = y2[js[m] * H + f];
        gc[m] = y2[js[m] * H + 64 + f];
    }

    float sacc = 0.f;
#pragma unroll
    for (int m = 0; m < MNBR; ++m) {
        int row = al * MNBR + m;
        float zf = sZ[row * 132 + f] + y1f + gf[m];
        float zc = sZ[row * 132 + 64 + f] + y1c + gc[m];
        zf = zf * s1f + h1f;
        zc = zc * s1c + h1c;
        sacc += sigmoidf(zf) * softplusf(zc);
    }
    float av = a[i * F + f];
    float res = softplusf(av + sacc * sS2[f] + sH2[f]);
    a[i * F + f] = res;
    unsigned short hh = f2bf(res);
    aHi[i * F + f] = hh;
    aLo[i * F + f] = f2bf(res - bf2f(hh));
}

// ---------------- pool ----------------
__global__ __launch_bounds__(256) void k_pool(const float* __restrict__ a,
                                              const int* __restrict__ seg,
                                              float* __restrict__ pool,
                                              float* __restrict__ cnt) {
    int idx = blockIdx.x * 256 + threadIdx.x;
    int n = idx >> 6, f = idx & 63;
    int c = seg[n];
    atomicAdd(&pool[c * F + f], a[idx]);
    if (f == 0) atomicAdd(&cnt[c], 1.f);
}

// ---------------- dense ----------------
__global__ __launch_bounds__(128) void k_dense(const float* __restrict__ pool,
                                               const float* __restrict__ cnt,
                                               const float* __restrict__ W,
                                               const float* __restrict__ b,
                                               float* __restrict__ crys) {
    int c = blockIdx.x;
    int h = threadIdx.x;
    __shared__ float sp[F];
    if (h < F) sp[h] = pool[c * F + h] / fmaxf(cnt[c], 1.f);
    __syncthreads();
    float acc = b[h];
#pragma unroll
    for (int k = 0; k < F; ++k) acc += sp[k] * W[k * H + h];
    crys[c * H + h] = softplusf(acc);
}

// ---------------- combine ----------------
__global__ __launch_bounds__(128) void k_combine(const float* __restrict__ cA,
                                                 const float* __restrict__ cB,
                                                 const float* __restrict__ ffW,
                                                 const float* __restrict__ ffb,
                                                 const float* __restrict__ outW,
                                                 const float* __restrict__ outb,
                                                 float* __restrict__ out) {
    int c = blockIdx.x;
    int h = threadIdx.x;
    __shared__ float sd[H];
    __shared__ float st[H];
    sd[h] = fabsf(cA[c * H + h] - cB[c * H + h]);
    __syncthreads();
    float acc = ffb[h];
#pragma unroll
    for (int k = 0; k < H; ++k) acc += sd[k] * ffW[k * H + h];
    st[h] = softplusf(acc) * outW[h];
    __syncthreads();
    for (int s = 64; s > 0; s >>= 1) {
        if (h < s) st[h] += st[h + s];
        __syncthreads();
    }
    if (h == 0) out[c] = st[0] + outb[0];
}

extern "C" void kernel_launch(void* const* d_in, const int* in_sizes, int n_in,
                              void* d_out, int out_size, void* d_ws, size_t ws_size,
                              hipStream_t stream) {
    const float* ffW  = (const float*)d_in[24];
    const float* ffb  = (const float*)d_in[25];
    const float* outW = (const float*)d_in[26];
    const float* outb = (const float*)d_in[27];

    float* ws = (float*)d_ws;
    float* a     = ws;                         // N*F (shared across branches)
    float* y1    = a + NATOM * F;              // N*H
    float* y2    = y1 + NATOM * H;             // N*H
    float* poolA = y2 + NATOM * H;             // NCRYS*F
    float* poolB = poolA + NCRYS * F;
    float* cntA  = poolB + NCRYS * F;          // NCRYS
    float* cntB  = cntA + NCRYS;
    float* crA   = cntB + NCRYS;               // NCRYS*H
    float* crB   = crA + NCRYS * H;
    unsigned* w3t  = (unsigned*)(crB + NCRYS * H);  // 24576
    unsigned* w12h = w3t + 24576;                   // 49152
    unsigned* w12l = w12h + 49152;                  // 49152
    unsigned* nbrb = w12l + 49152;                  // N*12*36
    unsigned short* aHi = (unsigned short*)(nbrb + (size_t)NATOM * MNBR * 36);  // N*F
    unsigned short* aLo = aHi + NATOM * F;

    hipMemsetAsync(poolA, 0, (size_t)(2 * NCRYS * F + 2 * NCRYS) * sizeof(float), stream);

    const float* convW_A = (const float*)d_in[6];
    const float* convW_B = (const float*)d_in[18];
    k_wcvt<<<288, 256, 0, stream>>>(convW_A, convW_B, w3t, w12h, w12l);

    for (int br = 0; br < 2; ++br) {
        int o = br * 12;
        const float* atom  = (const float*)d_in[o + 0];
        const float* nbrf  = (const float*)d_in[o + 1];
        const int*   nidx  = (const int*)d_in[o + 2];
        const int*   seg   = (const int*)d_in[o + 3];
        const float* embW  = (const float*)d_in[o + 4];
        const float* embb  = (const float*)d_in[o + 5];
        const float* convb = (const float*)d_in[o + 7];
        const float* bn1   = (const float*)d_in[o + 8];
        const float* bn2   = (const float*)d_in[o + 9];
        const float* denW  = (const float*)d_in[o + 10];
        const float* denb  = (const float*)d_in[o + 11];

        float* pool = br ? poolB : poolA;
        float* cnt  = br ? cntB : cntA;
        float* cr   = br ? crB : crA;

        k_nbrcvt<<<NATOM * MNBR * 36 / 256, 256, 0, stream>>>(nbrf, nbrb);
        k_embed<<<NATOM / 4, 256, 0, stream>>>(atom, embW, embb, a, aHi, aLo);
        for (int l = 0; l < NCONV; ++l) {
            int mat = br * 3 + l;
            const unsigned short* w3p  = (const unsigned short*)(w3t + (size_t)mat * 4096);
            const unsigned short* w12hp = (const unsigned short*)(w12h + (size_t)mat * 8192);
            const unsigned short* w12lp = (const unsigned short*)(w12l + (size_t)mat * 8192);
            k_y12<<<NATOM / 32, 256, 0, stream>>>(aHi, aLo, w12hp, w12lp, y1, y2);
            k_convfused<<<NATOM / 4, 256, 0, stream>>>(y1, y2, (const unsigned short*)nbrb, nidx,
                                                       w3p,
                                                       convb + l * H,
                                                       bn1 + l * 4 * H,
                                                       bn2 + l * 4 * F,
                                                       a, aHi, aLo);
        }
        k_pool<<<NATOM * F / 256, 256, 0, stream>>>(a, seg, pool, cnt);
        k_dense<<<NCRYS, 128, 0, stream>>>(pool, cnt, denW, denb, cr);
    }

    k_combine<<<NCRYS, 128, 0, stream>>>(crA, crB, ffW, ffb, outW, outb, (float*)d_out);
}

// Round 7
// 343.932 us; speedup vs baseline: 1.9882x; 1.2085x over previous
//
#include <hip/hip_runtime.h>

// Paired CGCNN (separated) — R6.
// R6: merge branch A and B into SINGLE dispatches (unified atom index
// 0..2N-1, branch = n>=N, branch-uniform pointer selects). 28 -> 12
// dispatches; dense+combine fused into k_head. Kernel bodies otherwise
// identical to R5 (validated numerics; absmax should stay 2.44e-3).

constexpr int NATOM = 20000;
constexpr int MNBR  = 12;
constexpr int ORIG  = 92;
constexpr int NBRF  = 41;
constexpr int F     = 64;
constexpr int H     = 128;
constexpr int NCONV = 3;
constexpr int NCRYS = 400;

#define DEVFN __device__ __forceinline__

typedef __attribute__((ext_vector_type(8))) short short8;   // 8 bf16 (4 VGPR)
typedef __attribute__((ext_vector_type(4))) float f32x4;    // MFMA acc

DEVFN float softplusf(float x) {
    return fmaxf(x, 0.f) + __logf(1.f + __expf(-fabsf(x)));
}
DEVFN float sigmoidf(float x) {
    return __builtin_amdgcn_rcpf(1.f + __expf(-x));
}
DEVFN unsigned short f2bf(float x) {  // RNE fp32->bf16
    union { float f; unsigned u; } v{x};
    unsigned r = v.u + 0x7FFF + ((v.u >> 16) & 1);
    return (unsigned short)(r >> 16);
}
DEVFN float bf2f(unsigned short h) {
    union { unsigned u; float f; } v;
    v.u = (unsigned)h << 16;
    return v.f;
}

template <typename T>
DEVFN const T* upt(const T* p) {
    unsigned long long v = (unsigned long long)p;
    unsigned lo = __builtin_amdgcn_readfirstlane((unsigned)v);
    unsigned hi = __builtin_amdgcn_readfirstlane((unsigned)(v >> 32));
    return (const T*)((((unsigned long long)hi) << 32) | lo);
}

// ---------------- wcvt: W3^T bf16 (6x128x64) + W12^T hi/lo bf16 (6x256x64) ----------------
__global__ __launch_bounds__(256) void k_wcvt(const float* __restrict__ convW_A,
                                              const float* __restrict__ convW_B,
                                              unsigned* __restrict__ w3t,
                                              unsigned* __restrict__ w12h,
                                              unsigned* __restrict__ w12l) {
    int e = blockIdx.x * 256 + threadIdx.x;  // 0..73727
    if (e < 24576) {
        int mat = e >> 12;
        int rem = e & 4095;
        int col = rem >> 5, kp = rem & 31, k = kp * 2;
        int br = mat / 3, l = mat - br * 3;
        const float* src = (br ? convW_B : convW_A) + (size_t)l * (2 * F + NBRF) * H + 128 * H;
        float v0 = (k < NBRF) ? src[k * H + col] : 0.f;
        float v1 = (k + 1 < NBRF) ? src[(k + 1) * H + col] : 0.f;
        w3t[e] = (unsigned)f2bf(v0) | ((unsigned)f2bf(v1) << 16);
    } else {
        int e2 = e - 24576;              // < 49152
        int mat = e2 >> 13;              // 6 mats x 8192 uints
        int rem = e2 & 8191;
        int col = rem >> 5, kp = rem & 31, k = kp * 2;
        const float* src = (mat >= 3 ? convW_B : convW_A) + (size_t)(mat % 3) * (2 * F + NBRF) * H;
        float v0, v1;
        if (col < 128) { v0 = src[k * H + col];              v1 = src[(k + 1) * H + col]; }
        else           { v0 = src[(64 + k) * H + col - 128]; v1 = src[(64 + k + 1) * H + col - 128]; }
        unsigned short h0 = f2bf(v0), h1 = f2bf(v1);
        w12h[e2] = (unsigned)h0 | ((unsigned)h1 << 16);
        w12l[e2] = (unsigned)f2bf(v0 - bf2f(h0)) | ((unsigned)f2bf(v1 - bf2f(h1)) << 16);
    }
}

// ---------------- nbrcvt (both branches): rows 0..2*N*12-1 ----------------
__global__ __launch_bounds__(256) void k_nbrcvt(const float* __restrict__ nbrA,
                                                const float* __restrict__ nbrB,
                                                unsigned* __restrict__ out) {
    int e = blockIdx.x * 256 + threadIdx.x;  // 0 .. 2*240000*36-1
    int row = e / 36;
    int kp = e - row * 36, k = kp * 2;
    int br = row >= NATOM * MNBR;
    const float* s = (br ? nbrB : nbrA) + (size_t)(row - br * NATOM * MNBR) * NBRF;
    float v0 = (k < NBRF) ? s[k] : 0.f;
    float v1 = (k + 1 < NBRF) ? s[k + 1] : 0.f;
    out[(size_t)row * 36 + kp] = (unsigned)f2bf(v0) | ((unsigned)f2bf(v1) << 16);
}

// ---------------- embed (both branches): n in 0..2N-1 ----------------
__global__ __launch_bounds__(256) void k_embed(const float* __restrict__ atomA,
                                               const float* __restrict__ atomB,
                                               const float* __restrict__ embWA,
                                               const float* __restrict__ embWB,
                                               const float* __restrict__ embbA,
                                               const float* __restrict__ embbB,
                                               float* __restrict__ out,
                                               unsigned short* __restrict__ aHi,
                                               unsigned short* __restrict__ aLo) {
    int t = threadIdx.x;
    int n = blockIdx.x * 4 + (t >> 6);       // 0..2N-1, block-uniform branch
    int br = n >= NATOM;
    const float* Wp = br ? embWB : embWA;
    __shared__ float sW[ORIG * F];
    for (int i = t; i < ORIG * F; i += 256) sW[i] = Wp[i];
    __syncthreads();
    int f = t & 63;
    int nl = n - br * NATOM;
    const float* ar = upt((br ? atomB : atomA) + (size_t)nl * ORIG);
    float acc = (br ? embbB : embbA)[f];
#pragma unroll
    for (int k = 0; k < ORIG; ++k) acc += ar[k] * sW[k * F + f];
    out[(size_t)n * F + f] = acc;
    unsigned short h = f2bf(acc);
    aHi[(size_t)n * F + f] = h;
    aLo[(size_t)n * F + f] = f2bf(acc - bf2f(h));
}

// ---------------- y12 (both branches, MFMA hi/lo): 32 atoms x 256 cols / block ----------------
__global__ __launch_bounds__(256, 2) void k_y12(const unsigned short* __restrict__ aHi,
                                                const unsigned short* __restrict__ aLo,
                                                const unsigned* __restrict__ w12h_base,
                                                const unsigned* __restrict__ w12l_base,
                                                int layer,
                                                float* __restrict__ y1,
                                                float* __restrict__ y2) {
    __shared__ __align__(16) unsigned short sH[32 * 72];
    __shared__ __align__(16) unsigned short sL[32 * 72];
    int t = threadIdx.x;
    int atom0 = blockIdx.x * 32;             // 0..2N-32, branch-uniform per block
    int br = atom0 >= NATOM;
    int mat = br * 3 + layer;
    const unsigned short* w12h = (const unsigned short*)(w12h_base + (size_t)mat * 8192);
    const unsigned short* w12l = (const unsigned short*)(w12l_base + (size_t)mat * 8192);
    {
        int row = t >> 3, sub = t & 7;
        *(short8*)(sH + row * 72 + sub * 8) = *(const short8*)(aHi + (size_t)(atom0 + row) * 64 + sub * 8);
        *(short8*)(sL + row * 72 + sub * 8) = *(const short8*)(aLo + (size_t)(atom0 + row) * 64 + sub * 8);
    }
    int w = t >> 6, lane = t & 63;
    int lr = lane & 15, lq = lane >> 4;

    short8 bh[2][4], bl[2][4];
#pragma unroll
    for (int kstep = 0; kstep < 2; ++kstep)
#pragma unroll
        for (int n = 0; n < 4; ++n) {
            int col = w * 64 + n * 16 + lr;
            size_t off = (size_t)col * 64 + kstep * 32 + lq * 8;
            bh[kstep][n] = *(const short8*)(w12h + off);
            bl[kstep][n] = *(const short8*)(w12l + off);
        }
    __syncthreads();

    f32x4 acc[4][2];
#pragma unroll
    for (int n = 0; n < 4; ++n)
#pragma unroll
        for (int r = 0; r < 2; ++r) acc[n][r] = f32x4{0.f, 0.f, 0.f, 0.f};

#pragma unroll
    for (int kstep = 0; kstep < 2; ++kstep) {
        int ks = kstep * 32 + lq * 8;
        short8 ah[2], al[2];
#pragma unroll
        for (int r = 0; r < 2; ++r) {
            ah[r] = *(const short8*)(sH + (r * 16 + lr) * 72 + ks);
            al[r] = *(const short8*)(sL + (r * 16 + lr) * 72 + ks);
        }
#pragma unroll
        for (int n = 0; n < 4; ++n)
#pragma unroll
            for (int r = 0; r < 2; ++r) {
                acc[n][r] = __builtin_amdgcn_mfma_f32_16x16x32_bf16(ah[r], bh[kstep][n], acc[n][r], 0, 0, 0);
                acc[n][r] = __builtin_amdgcn_mfma_f32_16x16x32_bf16(ah[r], bl[kstep][n], acc[n][r], 0, 0, 0);
                acc[n][r] = __builtin_amdgcn_mfma_f32_16x16x32_bf16(al[r], bh[kstep][n], acc[n][r], 0, 0, 0);
            }
    }

#pragma unroll
    for (int n = 0; n < 4; ++n) {
        int col = w * 64 + n * 16 + lr;
        float* dst = (col < 128) ? (y1 + col) : (y2 + col - 128);
#pragma unroll
        for (int r = 0; r < 2; ++r)
#pragma unroll
            for (int q = 0; q < 4; ++q) {
                int atom = atom0 + r * 16 + lq * 4 + q;
                dst[(size_t)atom * H] = acc[n][r][q];
            }
    }
}

// ---------------- fused conv layer (both branches) ----------------
__global__ __launch_bounds__(256, 4) void k_convfused(
        const float* __restrict__ y1,
        const float* __restrict__ y2,
        const unsigned short* __restrict__ nbrb,  // (2N*12, 72) bf16 unified
        const int* __restrict__ idxA,
        const int* __restrict__ idxB,
        const unsigned* __restrict__ w3t,
        int layer,
        const float* __restrict__ biasA, const float* __restrict__ biasB,
        const float* __restrict__ bn1A,  const float* __restrict__ bn1B,
        const float* __restrict__ bn2A,  const float* __restrict__ bn2B,
        float* __restrict__ a,
        unsigned short* __restrict__ aHi,
        unsigned short* __restrict__ aLo) {
    __shared__ __align__(16) unsigned char pool[27072];
    float* sZ  = (float*)pool;
    float* sS1 = (float*)(pool + 25344);
    float* sH1 = sS1 + 128;
    float* sS2 = sH1 + 128;
    float* sH2 = sS2 + 64;
    int*   sJ  = (int*)(pool + 26880);

    int t = threadIdx.x;
    int atom0 = blockIdx.x * 4;              // unified 0..2N-4
    int br = atom0 >= NATOM;
    int brOff = br * NATOM;
    int R0 = atom0 * MNBR;                   // unified nbrb row base
    const float* bias = br ? biasB : biasA;
    const float* bn1  = br ? bn1B : bn1A;
    const float* bn2  = br ? bn2B : bn2A;
    const unsigned short* w3l = (const unsigned short*)(w3t + (size_t)(br * 3 + layer) * 4096);

    // stage A: pure copy, 432 x 16B chunks
#pragma unroll
    for (int j = 0; j < 2; ++j) {
        int c = t + j * 256;
        if (c < 432) {
            int row = c / 9, sub = c - row * 9;
            short8 v = *(const short8*)(nbrb + (size_t)(R0 + row) * 72 + sub * 8);
            *(short8*)(pool + row * 144 + sub * 16) = v;
        }
    }
    if (t < 128) {
        float g = bn1[t], be = bn1[128 + t], mu = bn1[256 + t], va = bn1[384 + t];
        float s = g * rsqrtf(va + 1e-5f);
        sS1[t] = s;
        sH1[t] = be - mu * s + bias[t] * s;
    } else if (t < 192) {
        int u = t - 128;
        float g = bn2[u], be = bn2[64 + u], mu = bn2[128 + u], va = bn2[192 + u];
        float s = g * rsqrtf(va + 1e-5f);
        sS2[u] = s;
        sH2[u] = be - mu * s;
    }
    if (t < 48) sJ[t] = ((br ? idxB : idxA) + (size_t)(atom0 - brOff) * MNBR)[t];

    int w = t >> 6, lane = t & 63;
    int lr = lane & 15, lq = lane >> 4;
    int CB = w * 32;
    short8 bfr[2][2];
#pragma unroll
    for (int kstep = 0; kstep < 2; ++kstep)
#pragma unroll
        for (int n = 0; n < 2; ++n) {
            int col = CB + n * 16 + lr;
            int ks = kstep * 32 + lq * 8;
            bfr[kstep][n] = *(const short8*)(w3l + (size_t)col * 64 + ks);
        }
    __syncthreads();

    f32x4 acc[2][3];
#pragma unroll
    for (int n = 0; n < 2; ++n)
#pragma unroll
        for (int r = 0; r < 3; ++r) acc[n][r] = f32x4{0.f, 0.f, 0.f, 0.f};

#pragma unroll
    for (int kstep = 0; kstep < 2; ++kstep) {
        int ks = kstep * 32 + lq * 8;
        short8 af[3];
#pragma unroll
        for (int r = 0; r < 3; ++r) {
            int row = r * 16 + lr;
            af[r] = *(const short8*)(pool + (size_t)row * 144 + ks * 2);
        }
#pragma unroll
        for (int n = 0; n < 2; ++n)
#pragma unroll
            for (int r = 0; r < 3; ++r)
                acc[n][r] = __builtin_amdgcn_mfma_f32_16x16x32_bf16(af[r], bfr[kstep][n], acc[n][r], 0, 0, 0);
    }
    __syncthreads();

#pragma unroll
    for (int n = 0; n < 2; ++n)
#pragma unroll
        for (int r = 0; r < 3; ++r)
#pragma unroll
            for (int q = 0; q < 4; ++q) {
                int row = r * 16 + lq * 4 + q;
                int col = CB + n * 16 + lr;
                sZ[row * 132 + col] = acc[n][r][q];
            }
    __syncthreads();

    int al = t >> 6, f = t & 63;
    int i = atom0 + al;                      // unified
    float y1f = y1[(size_t)i * H + f], y1c = y1[(size_t)i * H + 64 + f];
    float s1f = sS1[f], h1f = sH1[f], s1c = sS1[64 + f], h1c = sH1[64 + f];

    int js[MNBR];
#pragma unroll
    for (int m = 0; m < MNBR; ++m) js[m] = sJ[al * MNBR + m] + brOff;
    float gf[MNBR], gc[MNBR];
#pragma unroll
    for (int m = 0; m < MNBR; ++m) {
        gf[m] = y2[(size_t)js[m] * H + f];
        gc[m] = y2[(size_t)js[m] * H + 64 + f];
    }

    float sacc = 0.f;
#pragma unroll
    for (int m = 0; m < MNBR; ++m) {
        int row = al * MNBR + m;
        float zf = sZ[row * 132 + f] + y1f + gf[m];
        float zc = sZ[row * 132 + 64 + f] + y1c + gc[m];
        zf = zf * s1f + h1f;
        zc = zc * s1c + h1c;
        sacc += sigmoidf(zf) * softplusf(zc);
    }
    float av = a[(size_t)i * F + f];
    float res = softplusf(av + sacc * sS2[f] + sH2[f]);
    a[(size_t)i * F + f] = res;
    unsigned short hh = f2bf(res);
    aHi[(size_t)i * F + f] = hh;
    aLo[(size_t)i * F + f] = f2bf(res - bf2f(hh));
}

// ---------------- pool (both branches) ----------------
__global__ __launch_bounds__(256) void k_pool(const float* __restrict__ a,
                                              const int* __restrict__ segA,
                                              const int* __restrict__ segB,
                                              float* __restrict__ poolU,
                                              float* __restrict__ cntU) {
    int idx = blockIdx.x * 256 + threadIdx.x;  // over 2*N*F
    int n = idx >> 6, f = idx & 63;
    int br = n >= NATOM;
    int c = (br ? segB[n - NATOM] : segA[n]) + br * NCRYS;
    atomicAdd(&poolU[(size_t)c * F + f], a[idx]);
    if (f == 0) atomicAdd(&cntU[c], 1.f);
}

// ---------------- head: dense(A) + dense(B) + |diff| + FF + out ----------------
__global__ __launch_bounds__(128) void k_head(const float* __restrict__ poolU,
                                              const float* __restrict__ cntU,
                                              const float* __restrict__ denWA,
                                              const float* __restrict__ denbA,
                                              const float* __restrict__ denWB,
                                              const float* __restrict__ denbB,
                                              const float* __restrict__ ffW,
                                              const float* __restrict__ ffb,
                                              const float* __restrict__ outW,
                                              const float* __restrict__ outb,
                                              float* __restrict__ out) {
    int c = blockIdx.x;
    int h = threadIdx.x;
    __shared__ float spA[F], spB[F], sd[H], st[H];
    if (h < F) spA[h] = poolU[(size_t)c * F + h] / fmaxf(cntU[c], 1.f);
    else {
        int u = h - F;
        spB[u] = poolU[(size_t)(c + NCRYS) * F + u] / fmaxf(cntU[c + NCRYS], 1.f);
    }
    __syncthreads();
    float accA = denbA[h], accB = denbB[h];
#pragma unroll
    for (int k = 0; k < F; ++k) {
        accA = fmaf(spA[k], denWA[k * H + h], accA);
        accB = fmaf(spB[k], denWB[k * H + h], accB);
    }
    sd[h] = fabsf(softplusf(accA) - softplusf(accB));
    __syncthreads();
    float acc = ffb[h];
#pragma unroll
    for (int k = 0; k < H; ++k) acc = fmaf(sd[k], ffW[k * H + h], acc);
    st[h] = softplusf(acc) * outW[h];
    __syncthreads();
    for (int s = 64; s > 0; s >>= 1) {
        if (h < s) st[h] += st[h + s];
        __syncthreads();
    }
    if (h == 0) out[c] = st[0] + outb[0];
}

extern "C" void kernel_launch(void* const* d_in, const int* in_sizes, int n_in,
                              void* d_out, int out_size, void* d_ws, size_t ws_size,
                              hipStream_t stream) {
    const float* atomA = (const float*)d_in[0];
    const float* nbrA  = (const float*)d_in[1];
    const int*   idxA  = (const int*)d_in[2];
    const int*   segA  = (const int*)d_in[3];
    const float* embWA = (const float*)d_in[4];
    const float* embbA = (const float*)d_in[5];
    const float* convWA = (const float*)d_in[6];
    const float* convbA = (const float*)d_in[7];
    const float* bn1A  = (const float*)d_in[8];
    const float* bn2A  = (const float*)d_in[9];
    const float* denWA = (const float*)d_in[10];
    const float* denbA = (const float*)d_in[11];
    const float* atomB = (const float*)d_in[12];
    const float* nbrB  = (const float*)d_in[13];
    const int*   idxB  = (const int*)d_in[14];
    const int*   segB  = (const int*)d_in[15];
    const float* embWB = (const float*)d_in[16];
    const float* embbB = (const float*)d_in[17];
    const float* convWB = (const float*)d_in[18];
    const float* convbB = (const float*)d_in[19];
    const float* bn1B  = (const float*)d_in[20];
    const float* bn2B  = (const float*)d_in[21];
    const float* denWB = (const float*)d_in[22];
    const float* denbB = (const float*)d_in[23];
    const float* ffW   = (const float*)d_in[24];
    const float* ffb   = (const float*)d_in[25];
    const float* outW  = (const float*)d_in[26];
    const float* outb  = (const float*)d_in[27];

    float* ws = (float*)d_ws;
    float* a     = ws;                              // 2N*F
    float* y1    = a + 2 * NATOM * F;               // 2N*H
    float* y2    = y1 + 2 * NATOM * H;              // 2N*H
    float* poolU = y2 + 2 * NATOM * H;              // 2*NCRYS*F
    float* cntU  = poolU + 2 * NCRYS * F;           // 2*NCRYS
    unsigned* w3t  = (unsigned*)(cntU + 2 * NCRYS); // 24576
    unsigned* w12h = w3t + 24576;                   // 49152
    unsigned* w12l = w12h + 49152;                  // 49152
    unsigned* nbrb = w12l + 49152;                  // 2N*12*36
    unsigned short* aHi = (unsigned short*)(nbrb + (size_t)2 * NATOM * MNBR * 36);  // 2N*F
    unsigned short* aLo = aHi + 2 * NATOM * F;

    hipMemsetAsync(poolU, 0, (size_t)(2 * NCRYS * F + 2 * NCRYS) * sizeof(float), stream);
    k_wcvt<<<288, 256, 0, stream>>>(convWA, convWB, w3t, w12h, w12l);
    k_nbrcvt<<<2 * NATOM * MNBR * 36 / 256, 256, 0, stream>>>(nbrA, nbrB, nbrb);
    k_embed<<<2 * NATOM / 4, 256, 0, stream>>>(atomA, atomB, embWA, embWB, embbA, embbB,
                                               a, aHi, aLo);
    for (int l = 0; l < NCONV; ++l) {
        k_y12<<<2 * NATOM / 32, 256, 0, stream>>>(aHi, aLo, w12h, w12l, l, y1, y2);
        k_convfused<<<2 * NATOM / 4, 256, 0, stream>>>(
            y1, y2, (const unsigned short*)nbrb, idxA, idxB, w3t, l,
            convbA + l * H, convbB + l * H,
            bn1A + l * 4 * H, bn1B + l * 4 * H,
            bn2A + l * 4 * F, bn2B + l * 4 * F,
            a, aHi, aLo);
    }
    k_pool<<<2 * NATOM * F / 256, 256, 0, stream>>>(a, segA, segB, poolU, cntU);
    k_head<<<NCRYS, 128, 0, stream>>>(poolU, cntU, denWA, denbA, denWB, denbB,
                                      ffW, ffb, outW, outb, (float*)d_out);
}

// Round 8
// 317.679 us; speedup vs baseline: 2.1525x; 1.0826x over previous
//
#include <hip/hip_runtime.h>

// Paired CGCNN (separated) — R7.
// R7 vs R6: (1) nbrb rows 72->48 ushorts (96B); k>=48 zeros created in LDS,
// not HBM. (2) k_nbrcvt vectorized: thread = uint4 output chunk (16B store).
// (3) k_pool fused into last conv layer's epilogue (atomicAdd poolU/cntU);
// last layer skips dead a/aHi/aLo writes. Arithmetic identical to R6.

constexpr int NATOM = 20000;
constexpr int MNBR  = 12;
constexpr int ORIG  = 92;
constexpr int NBRF  = 41;
constexpr int F     = 64;
constexpr int H     = 128;
constexpr int NCONV = 3;
constexpr int NCRYS = 400;

#define DEVFN __device__ __forceinline__

typedef __attribute__((ext_vector_type(8))) short short8;   // 8 bf16 (4 VGPR)
typedef __attribute__((ext_vector_type(4))) float f32x4;    // MFMA acc

DEVFN float softplusf(float x) {
    return fmaxf(x, 0.f) + __logf(1.f + __expf(-fabsf(x)));
}
DEVFN float sigmoidf(float x) {
    return __builtin_amdgcn_rcpf(1.f + __expf(-x));
}
DEVFN unsigned short f2bf(float x) {  // RNE fp32->bf16
    union { float f; unsigned u; } v{x};
    unsigned r = v.u + 0x7FFF + ((v.u >> 16) & 1);
    return (unsigned short)(r >> 16);
}
DEVFN float bf2f(unsigned short h) {
    union { unsigned u; float f; } v;
    v.u = (unsigned)h << 16;
    return v.f;
}
DEVFN unsigned pk2(float a, float b) {
    return (unsigned)f2bf(a) | ((unsigned)f2bf(b) << 16);
}

template <typename T>
DEVFN const T* upt(const T* p) {
    unsigned long long v = (unsigned long long)p;
    unsigned lo = __builtin_amdgcn_readfirstlane((unsigned)v);
    unsigned hi = __builtin_amdgcn_readfirstlane((unsigned)(v >> 32));
    return (const T*)((((unsigned long long)hi) << 32) | lo);
}

// ---------------- wcvt: W3^T bf16 (6x128x64) + W12^T hi/lo bf16 (6x256x64) ----------------
__global__ __launch_bounds__(256) void k_wcvt(const float* __restrict__ convW_A,
                                              const float* __restrict__ convW_B,
                                              unsigned* __restrict__ w3t,
                                              unsigned* __restrict__ w12h,
                                              unsigned* __restrict__ w12l) {
    int e = blockIdx.x * 256 + threadIdx.x;  // 0..73727
    if (e < 24576) {
        int mat = e >> 12;
        int rem = e & 4095;
        int col = rem >> 5, kp = rem & 31, k = kp * 2;
        int br = mat / 3, l = mat - br * 3;
        const float* src = (br ? convW_B : convW_A) + (size_t)l * (2 * F + NBRF) * H + 128 * H;
        float v0 = (k < NBRF) ? src[k * H + col] : 0.f;
        float v1 = (k + 1 < NBRF) ? src[(k + 1) * H + col] : 0.f;
        w3t[e] = pk2(v0, v1);
    } else {
        int e2 = e - 24576;              // < 49152
        int mat = e2 >> 13;              // 6 mats x 8192 uints
        int rem = e2 & 8191;
        int col = rem >> 5, kp = rem & 31, k = kp * 2;
        const float* src = (mat >= 3 ? convW_B : convW_A) + (size_t)(mat % 3) * (2 * F + NBRF) * H;
        float v0, v1;
        if (col < 128) { v0 = src[k * H + col];              v1 = src[(k + 1) * H + col]; }
        else           { v0 = src[(64 + k) * H + col - 128]; v1 = src[(64 + k + 1) * H + col - 128]; }
        unsigned short h0 = f2bf(v0), h1 = f2bf(v1);
        w12h[e2] = (unsigned)h0 | ((unsigned)h1 << 16);
        w12l[e2] = (unsigned)f2bf(v0 - bf2f(h0)) | ((unsigned)f2bf(v1 - bf2f(h1)) << 16);
    }
}

// ---------------- nbrcvt: rows (2N*12) of 41 fp32 -> 48 bf16 (96B); uint4 stores ----------------
__global__ __launch_bounds__(256) void k_nbrcvt(const float* __restrict__ nbrA,
                                                const float* __restrict__ nbrB,
                                                uint4* __restrict__ out) {
    int e = blockIdx.x * 256 + threadIdx.x;  // 0 .. 2*240000*6-1
    int row = e / 6, sub = e - row * 6;
    int br = row >= NATOM * MNBR;
    const float* s = (br ? nbrB : nbrA) + (size_t)(row - br * NATOM * MNBR) * NBRF;
    int k0 = sub * 8;
    float v[8];
#pragma unroll
    for (int j = 0; j < 8; ++j) v[j] = (k0 + j < NBRF) ? s[k0 + j] : 0.f;
    uint4 o;
    o.x = pk2(v[0], v[1]);
    o.y = pk2(v[2], v[3]);
    o.z = pk2(v[4], v[5]);
    o.w = pk2(v[6], v[7]);
    out[e] = o;
}

// ---------------- embed (both branches) ----------------
__global__ __launch_bounds__(256) void k_embed(const float* __restrict__ atomA,
                                               const float* __restrict__ atomB,
                                               const float* __restrict__ embWA,
                                               const float* __restrict__ embWB,
                                               const float* __restrict__ embbA,
                                               const float* __restrict__ embbB,
                                               float* __restrict__ out,
                                               unsigned short* __restrict__ aHi,
                                               unsigned short* __restrict__ aLo) {
    int t = threadIdx.x;
    int n = blockIdx.x * 4 + (t >> 6);       // block-uniform branch (grid half-split)
    int br = n >= NATOM;
    const float* Wp = br ? embWB : embWA;
    __shared__ float sW[ORIG * F];
    for (int i = t; i < ORIG * F; i += 256) sW[i] = Wp[i];
    __syncthreads();
    int f = t & 63;
    int nl = n - br * NATOM;
    const float* ar = upt((br ? atomB : atomA) + (size_t)nl * ORIG);
    float acc = (br ? embbB : embbA)[f];
#pragma unroll
    for (int k = 0; k < ORIG; ++k) acc += ar[k] * sW[k * F + f];
    out[(size_t)n * F + f] = acc;
    unsigned short h = f2bf(acc);
    aHi[(size_t)n * F + f] = h;
    aLo[(size_t)n * F + f] = f2bf(acc - bf2f(h));
}

// ---------------- y12 (both branches, MFMA hi/lo): 32 atoms x 256 cols / block ----------------
__global__ __launch_bounds__(256, 2) void k_y12(const unsigned short* __restrict__ aHi,
                                                const unsigned short* __restrict__ aLo,
                                                const unsigned* __restrict__ w12h_base,
                                                const unsigned* __restrict__ w12l_base,
                                                int layer,
                                                float* __restrict__ y1,
                                                float* __restrict__ y2) {
    __shared__ __align__(16) unsigned short sH[32 * 72];
    __shared__ __align__(16) unsigned short sL[32 * 72];
    int t = threadIdx.x;
    int atom0 = blockIdx.x * 32;
    int br = atom0 >= NATOM;
    int mat = br * 3 + layer;
    const unsigned short* w12h = (const unsigned short*)(w12h_base + (size_t)mat * 8192);
    const unsigned short* w12l = (const unsigned short*)(w12l_base + (size_t)mat * 8192);
    {
        int row = t >> 3, sub = t & 7;
        *(short8*)(sH + row * 72 + sub * 8) = *(const short8*)(aHi + (size_t)(atom0 + row) * 64 + sub * 8);
        *(short8*)(sL + row * 72 + sub * 8) = *(const short8*)(aLo + (size_t)(atom0 + row) * 64 + sub * 8);
    }
    int w = t >> 6, lane = t & 63;
    int lr = lane & 15, lq = lane >> 4;

    short8 bh[2][4], bl[2][4];
#pragma unroll
    for (int kstep = 0; kstep < 2; ++kstep)
#pragma unroll
        for (int n = 0; n < 4; ++n) {
            int col = w * 64 + n * 16 + lr;
            size_t off = (size_t)col * 64 + kstep * 32 + lq * 8;
            bh[kstep][n] = *(const short8*)(w12h + off);
            bl[kstep][n] = *(const short8*)(w12l + off);
        }
    __syncthreads();

    f32x4 acc[4][2];
#pragma unroll
    for (int n = 0; n < 4; ++n)
#pragma unroll
        for (int r = 0; r < 2; ++r) acc[n][r] = f32x4{0.f, 0.f, 0.f, 0.f};

#pragma unroll
    for (int kstep = 0; kstep < 2; ++kstep) {
        int ks = kstep * 32 + lq * 8;
        short8 ah[2], al[2];
#pragma unroll
        for (int r = 0; r < 2; ++r) {
            ah[r] = *(const short8*)(sH + (r * 16 + lr) * 72 + ks);
            al[r] = *(const short8*)(sL + (r * 16 + lr) * 72 + ks);
        }
#pragma unroll
        for (int n = 0; n < 4; ++n)
#pragma unroll
            for (int r = 0; r < 2; ++r) {
                acc[n][r] = __builtin_amdgcn_mfma_f32_16x16x32_bf16(ah[r], bh[kstep][n], acc[n][r], 0, 0, 0);
                acc[n][r] = __builtin_amdgcn_mfma_f32_16x16x32_bf16(ah[r], bl[kstep][n], acc[n][r], 0, 0, 0);
                acc[n][r] = __builtin_amdgcn_mfma_f32_16x16x32_bf16(al[r], bh[kstep][n], acc[n][r], 0, 0, 0);
            }
    }

#pragma unroll
    for (int n = 0; n < 4; ++n) {
        int col = w * 64 + n * 16 + lr;
        float* dst = (col < 128) ? (y1 + col) : (y2 + col - 128);
#pragma unroll
        for (int r = 0; r < 2; ++r)
#pragma unroll
            for (int q = 0; q < 4; ++q) {
                int atom = atom0 + r * 16 + lq * 4 + q;
                dst[(size_t)atom * H] = acc[n][r][q];
            }
    }
}

// ---------------- fused conv layer (both branches); last layer fuses pool ----------------
__global__ __launch_bounds__(256, 4) void k_convfused(
        const float* __restrict__ y1,
        const float* __restrict__ y2,
        const unsigned short* __restrict__ nbrb,  // (2N*12, 48) bf16
        const int* __restrict__ idxA,
        const int* __restrict__ idxB,
        const unsigned* __restrict__ w3t,
        int layer, int last,
        const float* __restrict__ biasA, const float* __restrict__ biasB,
        const float* __restrict__ bn1A,  const float* __restrict__ bn1B,
        const float* __restrict__ bn2A,  const float* __restrict__ bn2B,
        const int* __restrict__ segA,    const int* __restrict__ segB,
        float* __restrict__ a,
        unsigned short* __restrict__ aHi,
        unsigned short* __restrict__ aLo,
        float* __restrict__ poolU,
        float* __restrict__ cntU) {
    __shared__ __align__(16) unsigned char pool[27072];
    float* sZ  = (float*)pool;
    float* sS1 = (float*)(pool + 25344);
    float* sH1 = sS1 + 128;
    float* sS2 = sH1 + 128;
    float* sH2 = sS2 + 64;
    int*   sJ  = (int*)(pool + 26880);

    int t = threadIdx.x;
    int atom0 = blockIdx.x * 4;              // unified 0..2N-4
    int br = atom0 >= NATOM;
    int brOff = br * NATOM;
    int R0 = atom0 * MNBR;
    const float* bias = br ? biasB : biasA;
    const float* bn1  = br ? bn1B : bn1A;
    const float* bn2  = br ? bn2B : bn2A;
    const unsigned short* w3l = (const unsigned short*)(w3t + (size_t)(br * 3 + layer) * 4096);

    // stage A: 288 data chunks (6x16B per row) + 96 zero chunks (k=48..63)
#pragma unroll
    for (int j = 0; j < 2; ++j) {
        int c = t + j * 256;
        if (c < 288) {
            int row = c / 6, sub = c - row * 6;
            short8 v = *(const short8*)(nbrb + (size_t)(R0 + row) * 48 + sub * 8);
            *(short8*)(pool + row * 144 + sub * 16) = v;
        } else if (c < 384) {
            int z = c - 288;
            int row = z >> 1, sub = 6 + (z & 1);
            *(short8*)(pool + row * 144 + sub * 16) = short8{0, 0, 0, 0, 0, 0, 0, 0};
        }
    }
    if (t < 128) {
        float g = bn1[t], be = bn1[128 + t], mu = bn1[256 + t], va = bn1[384 + t];
        float s = g * rsqrtf(va + 1e-5f);
        sS1[t] = s;
        sH1[t] = be - mu * s + bias[t] * s;
    } else if (t < 192) {
        int u = t - 128;
        float g = bn2[u], be = bn2[64 + u], mu = bn2[128 + u], va = bn2[192 + u];
        float s = g * rsqrtf(va + 1e-5f);
        sS2[u] = s;
        sH2[u] = be - mu * s;
    }
    if (t < 48) sJ[t] = ((br ? idxB : idxA) + (size_t)(atom0 - brOff) * MNBR)[t];

    int w = t >> 6, lane = t & 63;
    int lr = lane & 15, lq = lane >> 4;
    int CB = w * 32;
    short8 bfr[2][2];
#pragma unroll
    for (int kstep = 0; kstep < 2; ++kstep)
#pragma unroll
        for (int n = 0; n < 2; ++n) {
            int col = CB + n * 16 + lr;
            int ks = kstep * 32 + lq * 8;
            bfr[kstep][n] = *(const short8*)(w3l + (size_t)col * 64 + ks);
        }
    __syncthreads();

    f32x4 acc[2][3];
#pragma unroll
    for (int n = 0; n < 2; ++n)
#pragma unroll
        for (int r = 0; r < 3; ++r) acc[n][r] = f32x4{0.f, 0.f, 0.f, 0.f};

#pragma unroll
    for (int kstep = 0; kstep < 2; ++kstep) {
        int ks = kstep * 32 + lq * 8;
        short8 af[3];
#pragma unroll
        for (int r = 0; r < 3; ++r) {
            int row = r * 16 + lr;
            af[r] = *(const short8*)(pool + (size_t)row * 144 + ks * 2);
        }
#pragma unroll
        for (int n = 0; n < 2; ++n)
#pragma unroll
            for (int r = 0; r < 3; ++r)
                acc[n][r] = __builtin_amdgcn_mfma_f32_16x16x32_bf16(af[r], bfr[kstep][n], acc[n][r], 0, 0, 0);
    }
    __syncthreads();

#pragma unroll
    for (int n = 0; n < 2; ++n)
#pragma unroll
        for (int r = 0; r < 3; ++r)
#pragma unroll
            for (int q = 0; q < 4; ++q) {
                int row = r * 16 + lq * 4 + q;
                int col = CB + n * 16 + lr;
                sZ[row * 132 + col] = acc[n][r][q];
            }
    __syncthreads();

    int al = t >> 6, f = t & 63;
    int i = atom0 + al;
    float y1f = y1[(size_t)i * H + f], y1c = y1[(size_t)i * H + 64 + f];
    float s1f = sS1[f], h1f = sH1[f], s1c = sS1[64 + f], h1c = sH1[64 + f];

    int js[MNBR];
#pragma unroll
    for (int m = 0; m < MNBR; ++m) js[m] = sJ[al * MNBR + m] + brOff;
    float gf[MNBR], gc[MNBR];
#pragma unroll
    for (int m = 0; m < MNBR; ++m) {
        gf[m] = y2[(size_t)js[m] * H + f];
        gc[m] = y2[(size_t)js[m] * H + 64 + f];
    }

    float sacc = 0.f;
#pragma unroll
    for (int m = 0; m < MNBR; ++m) {
        int row = al * MNBR + m;
        float zf = sZ[row * 132 + f] + y1f + gf[m];
        float zc = sZ[row * 132 + 64 + f] + y1c + gc[m];
        zf = zf * s1f + h1f;
        zc = zc * s1c + h1c;
        sacc += sigmoidf(zf) * softplusf(zc);
    }
    float av = a[(size_t)i * F + f];
    float res = softplusf(av + sacc * sS2[f] + sH2[f]);
    if (!last) {
        a[(size_t)i * F + f] = res;
        unsigned short hh = f2bf(res);
        aHi[(size_t)i * F + f] = hh;
        aLo[(size_t)i * F + f] = f2bf(res - bf2f(hh));
    } else {
        const int* segp = upt((br ? segB : segA) + (i - brOff));
        int c = segp[0] + br * NCRYS;
        atomicAdd(&poolU[(size_t)c * F + f], res);
        if (f == 0) atomicAdd(&cntU[c], 1.f);
    }
}

// ---------------- head: dense(A) + dense(B) + |diff| + FF + out ----------------
__global__ __launch_bounds__(128) void k_head(const float* __restrict__ poolU,
                                              const float* __restrict__ cntU,
                                              const float* __restrict__ denWA,
                                              const float* __restrict__ denbA,
                                              const float* __restrict__ denWB,
                                              const float* __restrict__ denbB,
                                              const float* __restrict__ ffW,
                                              const float* __restrict__ ffb,
                                              const float* __restrict__ outW,
                                              const float* __restrict__ outb,
                                              float* __restrict__ out) {
    int c = blockIdx.x;
    int h = threadIdx.x;
    __shared__ float spA[F], spB[F], sd[H], st[H];
    if (h < F) spA[h] = poolU[(size_t)c * F + h] / fmaxf(cntU[c], 1.f);
    else {
        int u = h - F;
        spB[u] = poolU[(size_t)(c + NCRYS) * F + u] / fmaxf(cntU[c + NCRYS], 1.f);
    }
    __syncthreads();
    float accA = denbA[h], accB = denbB[h];
#pragma unroll
    for (int k = 0; k < F; ++k) {
        accA = fmaf(spA[k], denWA[k * H + h], accA);
        accB = fmaf(spB[k], denWB[k * H + h], accB);
    }
    sd[h] = fabsf(softplusf(accA) - softplusf(accB));
    __syncthreads();
    float acc = ffb[h];
#pragma unroll
    for (int k = 0; k < H; ++k) acc = fmaf(sd[k], ffW[k * H + h], acc);
    st[h] = softplusf(acc) * outW[h];
    __syncthreads();
    for (int s = 64; s > 0; s >>= 1) {
        if (h < s) st[h] += st[h + s];
        __syncthreads();
    }
    if (h == 0) out[c] = st[0] + outb[0];
}

extern "C" void kernel_launch(void* const* d_in, const int* in_sizes, int n_in,
                              void* d_out, int out_size, void* d_ws, size_t ws_size,
                              hipStream_t stream) {
    const float* atomA = (const float*)d_in[0];
    const float* nbrA  = (const float*)d_in[1];
    const int*   idxA  = (const int*)d_in[2];
    const int*   segA  = (const int*)d_in[3];
    const float* embWA = (const float*)d_in[4];
    const float* embbA = (const float*)d_in[5];
    const float* convWA = (const float*)d_in[6];
    const float* convbA = (const float*)d_in[7];
    const float* bn1A  = (const float*)d_in[8];
    const float* bn2A  = (const float*)d_in[9];
    const float* denWA = (const float*)d_in[10];
    const float* denbA = (const float*)d_in[11];
    const float* atomB = (const float*)d_in[12];
    const float* nbrB  = (const float*)d_in[13];
    const int*   idxB  = (const int*)d_in[14];
    const int*   segB  = (const int*)d_in[15];
    const float* embWB = (const float*)d_in[16];
    const float* embbB = (const float*)d_in[17];
    const float* convWB = (const float*)d_in[18];
    const float* convbB = (const float*)d_in[19];
    const float* bn1B  = (const float*)d_in[20];
    const float* bn2B  = (const float*)d_in[21];
    const float* denWB = (const float*)d_in[22];
    const float* denbB = (const float*)d_in[23];
    const float* ffW   = (const float*)d_in[24];
    const float* ffb   = (const float*)d_in[25];
    const float* outW  = (const float*)d_in[26];
    const float* outb  = (const float*)d_in[27];

    float* ws = (float*)d_ws;
    float* a     = ws;                              // 2N*F
    float* y1    = a + 2 * NATOM * F;               // 2N*H
    float* y2    = y1 + 2 * NATOM * H;              // 2N*H
    float* poolU = y2 + 2 * NATOM * H;              // 2*NCRYS*F
    float* cntU  = poolU + 2 * NCRYS * F;           // 2*NCRYS
    unsigned* w3t  = (unsigned*)(cntU + 2 * NCRYS); // 24576
    unsigned* w12h = w3t + 24576;                   // 49152
    unsigned* w12l = w12h + 49152;                  // 49152
    unsigned* nbrb = w12l + 49152;                  // 2N*12*24 uints (96B rows)
    unsigned short* aHi = (unsigned short*)(nbrb + (size_t)2 * NATOM * MNBR * 24);  // 2N*F
    unsigned short* aLo = aHi + 2 * NATOM * F;

    hipMemsetAsync(poolU, 0, (size_t)(2 * NCRYS * F + 2 * NCRYS) * sizeof(float), stream);
    k_wcvt<<<288, 256, 0, stream>>>(convWA, convWB, w3t, w12h, w12l);
    k_nbrcvt<<<2 * NATOM * MNBR * 6 / 256, 256, 0, stream>>>(nbrA, nbrB, (uint4*)nbrb);
    k_embed<<<2 * NATOM / 4, 256, 0, stream>>>(atomA, atomB, embWA, embWB, embbA, embbB,
                                               a, aHi, aLo);
    for (int l = 0; l < NCONV; ++l) {
        k_y12<<<2 * NATOM / 32, 256, 0, stream>>>(aHi, aLo, w12h, w12l, l, y1, y2);
        k_convfused<<<2 * NATOM / 4, 256, 0, stream>>>(
            y1, y2, (const unsigned short*)nbrb, idxA, idxB, w3t, l, (l == NCONV - 1) ? 1 : 0,
            convbA + l * H, convbB + l * H,
            bn1A + l * 4 * H, bn1B + l * 4 * H,
            bn2A + l * 4 * F, bn2B + l * 4 * F,
            segA, segB,
            a, aHi, aLo, poolU, cntU);
    }
    k_head<<<NCRYS, 128, 0, stream>>>(poolU, cntU, denWA, denbA, denWB, denbB,
                                      ffW, ffb, outW, outb, (float*)d_out);
}

// Round 9
// 291.259 us; speedup vs baseline: 2.3477x; 1.0907x over previous
//
#include <hip/hip_runtime.h>

// Paired CGCNN (separated) — R9.
// R9 vs R8: (1) pool un-fused (atomic contention stretched conv3 to 99us);
// (2) fp32 `a` buffer eliminated — residual carried as aHi/aLo (hi+lo);
// (3) embed is now an MFMA GEMM with hi/lo split (A staged LDS stride-104,
// B=embW hi/lo precomputed in k_wcvt, K padded 92->96, 18 MFMA/wave).

constexpr int NATOM = 20000;
constexpr int MNBR  = 12;
constexpr int ORIG  = 92;
constexpr int NBRF  = 41;
constexpr int F     = 64;
constexpr int H     = 128;
constexpr int NCONV = 3;
constexpr int NCRYS = 400;

#define DEVFN __device__ __forceinline__

typedef __attribute__((ext_vector_type(8))) short short8;   // 8 bf16 (4 VGPR)
typedef __attribute__((ext_vector_type(4))) float f32x4;    // MFMA acc

DEVFN float softplusf(float x) {
    return fmaxf(x, 0.f) + __logf(1.f + __expf(-fabsf(x)));
}
DEVFN float sigmoidf(float x) {
    return __builtin_amdgcn_rcpf(1.f + __expf(-x));
}
DEVFN unsigned short f2bf(float x) {  // RNE fp32->bf16
    union { float f; unsigned u; } v{x};
    unsigned r = v.u + 0x7FFF + ((v.u >> 16) & 1);
    return (unsigned short)(r >> 16);
}
DEVFN float bf2f(unsigned short h) {
    union { unsigned u; float f; } v;
    v.u = (unsigned)h << 16;
    return v.f;
}
DEVFN unsigned pk2(float a, float b) {
    return (unsigned)f2bf(a) | ((unsigned)f2bf(b) << 16);
}

template <typename T>
DEVFN const T* upt(const T* p) {
    unsigned long long v = (unsigned long long)p;
    unsigned lo = __builtin_amdgcn_readfirstlane((unsigned)v);
    unsigned hi = __builtin_amdgcn_readfirstlane((unsigned)(v >> 32));
    return (const T*)((((unsigned long long)hi) << 32) | lo);
}

// ------- wcvt: W3^T bf16 (6x128x64) + W12^T hi/lo (6x256x64) + embW^T hi/lo (2x64x96) -------
__global__ __launch_bounds__(256) void k_wcvt(const float* __restrict__ convW_A,
                                              const float* __restrict__ convW_B,
                                              const float* __restrict__ embWA,
                                              const float* __restrict__ embWB,
                                              unsigned* __restrict__ w3t,
                                              unsigned* __restrict__ w12h,
                                              unsigned* __restrict__ w12l,
                                              unsigned* __restrict__ embh,
                                              unsigned* __restrict__ embl) {
    int e = blockIdx.x * 256 + threadIdx.x;  // 0..79871
    if (e < 24576) {
        int mat = e >> 12;
        int rem = e & 4095;
        int col = rem >> 5, kp = rem & 31, k = kp * 2;
        int br = mat / 3, l = mat - br * 3;
        const float* src = (br ? convW_B : convW_A) + (size_t)l * (2 * F + NBRF) * H + 128 * H;
        float v0 = (k < NBRF) ? src[k * H + col] : 0.f;
        float v1 = (k + 1 < NBRF) ? src[(k + 1) * H + col] : 0.f;
        w3t[e] = pk2(v0, v1);
    } else if (e < 73728) {
        int e2 = e - 24576;              // < 49152
        int mat = e2 >> 13;              // 6 mats x 8192 uints
        int rem = e2 & 8191;
        int col = rem >> 5, kp = rem & 31, k = kp * 2;
        const float* src = (mat >= 3 ? convW_B : convW_A) + (size_t)(mat % 3) * (2 * F + NBRF) * H;
        float v0, v1;
        if (col < 128) { v0 = src[k * H + col];              v1 = src[(k + 1) * H + col]; }
        else           { v0 = src[(64 + k) * H + col - 128]; v1 = src[(64 + k + 1) * H + col - 128]; }
        unsigned short h0 = f2bf(v0), h1 = f2bf(v1);
        w12h[e2] = (unsigned)h0 | ((unsigned)h1 << 16);
        w12l[e2] = (unsigned)f2bf(v0 - bf2f(h0)) | ((unsigned)f2bf(v1 - bf2f(h1)) << 16);
    } else {
        int e3 = e - 73728;              // < 6144 : embW^T, 2 br x 64 cols x 48 kp
        int br = e3 / 3072;
        int rem = e3 - br * 3072;
        int col = rem / 48, kp = rem - col * 48, k = kp * 2;
        const float* src = br ? embWB : embWA;  // (92,64)
        float v0 = (k < ORIG) ? src[k * F + col] : 0.f;
        float v1 = (k + 1 < ORIG) ? src[(k + 1) * F + col] : 0.f;
        unsigned short h0 = f2bf(v0), h1 = f2bf(v1);
        embh[e3] = (unsigned)h0 | ((unsigned)h1 << 16);
        embl[e3] = (unsigned)f2bf(v0 - bf2f(h0)) | ((unsigned)f2bf(v1 - bf2f(h1)) << 16);
    }
}

// ---------------- nbrcvt: rows (2N*12) of 41 fp32 -> 48 bf16 (96B); uint4 stores ----------------
__global__ __launch_bounds__(256) void k_nbrcvt(const float* __restrict__ nbrA,
                                                const float* __restrict__ nbrB,
                                                uint4* __restrict__ out) {
    int e = blockIdx.x * 256 + threadIdx.x;  // 0 .. 2*240000*6-1
    int row = e / 6, sub = e - row * 6;
    int br = row >= NATOM * MNBR;
    const float* s = (br ? nbrB : nbrA) + (size_t)(row - br * NATOM * MNBR) * NBRF;
    int k0 = sub * 8;
    float v[8];
#pragma unroll
    for (int j = 0; j < 8; ++j) v[j] = (k0 + j < NBRF) ? s[k0 + j] : 0.f;
    uint4 o;
    o.x = pk2(v[0], v[1]);
    o.y = pk2(v[2], v[3]);
    o.z = pk2(v[4], v[5]);
    o.w = pk2(v[6], v[7]);
    out[e] = o;
}

// ---------------- embed (MFMA hi/lo): 32 atoms x 64 cols per block ----------------
__global__ __launch_bounds__(256) void k_embed(const float* __restrict__ atomA,
                                               const float* __restrict__ atomB,
                                               const unsigned* __restrict__ embh,
                                               const unsigned* __restrict__ embl,
                                               const float* __restrict__ embbA,
                                               const float* __restrict__ embbB,
                                               unsigned short* __restrict__ aHi,
                                               unsigned short* __restrict__ aLo) {
    __shared__ __align__(16) unsigned short sH[32 * 104];  // stride 104 ushort = 208B
    __shared__ __align__(16) unsigned short sL[32 * 104];
    int t = threadIdx.x;
    int atom0 = blockIdx.x * 32;             // 2N/32 = 1250 blocks; clean A/B split at 625
    int br = atom0 >= NATOM;
    const float* src = (br ? atomB : atomA) + (size_t)(atom0 - br * NATOM) * ORIG;

    // stage A: 32 rows x 92 floats = 736 float4 chunks -> hi/lo bf16; zero-pad k=92..95
#pragma unroll
    for (int it = 0; it < 3; ++it) {
        int idx = t + it * 256;
        if (idx < 736) {
            int row = idx / 23, sub = idx - row * 23;
            float4 v = *(const float4*)(src + (size_t)row * ORIG + sub * 4);
            int o = row * 104 + sub * 4;
            unsigned short h0 = f2bf(v.x), h1 = f2bf(v.y), h2 = f2bf(v.z), h3 = f2bf(v.w);
            *(uint2*)(sH + o) = uint2{(unsigned)h0 | ((unsigned)h1 << 16),
                                      (unsigned)h2 | ((unsigned)h3 << 16)};
            *(uint2*)(sL + o) = uint2{(unsigned)f2bf(v.x - bf2f(h0)) | ((unsigned)f2bf(v.y - bf2f(h1)) << 16),
                                      (unsigned)f2bf(v.z - bf2f(h2)) | ((unsigned)f2bf(v.w - bf2f(h3)) << 16)};
        } else if (idx < 768) {
            int row = idx - 736;
            *(uint2*)(sH + row * 104 + 92) = uint2{0, 0};
            *(uint2*)(sL + row * 104 + 92) = uint2{0, 0};
        }
    }

    int w = t >> 6, lane = t & 63;
    int lr = lane & 15, lq = lane >> 4;
    int col = w * 16 + lr;

    // B frags: direct global->VGPR, 3 ksteps
    const unsigned short* bh_base = (const unsigned short*)embh + (size_t)br * 6144 + (size_t)col * 96;
    const unsigned short* bl_base = (const unsigned short*)embl + (size_t)br * 6144 + (size_t)col * 96;
    short8 bh[3], bl[3];
#pragma unroll
    for (int ks = 0; ks < 3; ++ks) {
        bh[ks] = *(const short8*)(bh_base + ks * 32 + lq * 8);
        bl[ks] = *(const short8*)(bl_base + ks * 32 + lq * 8);
    }
    __syncthreads();

    f32x4 acc[2];
    acc[0] = f32x4{0.f, 0.f, 0.f, 0.f};
    acc[1] = f32x4{0.f, 0.f, 0.f, 0.f};
#pragma unroll
    for (int ks = 0; ks < 3; ++ks) {
        int ko = ks * 32 + lq * 8;
        short8 ah[2], al[2];
#pragma unroll
        for (int r = 0; r < 2; ++r) {
            ah[r] = *(const short8*)(sH + (r * 16 + lr) * 104 + ko);
            al[r] = *(const short8*)(sL + (r * 16 + lr) * 104 + ko);
        }
#pragma unroll
        for (int r = 0; r < 2; ++r) {
            acc[r] = __builtin_amdgcn_mfma_f32_16x16x32_bf16(ah[r], bh[ks], acc[r], 0, 0, 0);
            acc[r] = __builtin_amdgcn_mfma_f32_16x16x32_bf16(ah[r], bl[ks], acc[r], 0, 0, 0);
            acc[r] = __builtin_amdgcn_mfma_f32_16x16x32_bf16(al[r], bh[ks], acc[r], 0, 0, 0);
        }
    }

    float bias = (br ? embbB : embbA)[col];
#pragma unroll
    for (int r = 0; r < 2; ++r)
#pragma unroll
        for (int q = 0; q < 4; ++q) {
            int atom = atom0 + r * 16 + lq * 4 + q;
            float val = acc[r][q] + bias;
            unsigned short h = f2bf(val);
            aHi[(size_t)atom * F + col] = h;
            aLo[(size_t)atom * F + col] = f2bf(val - bf2f(h));
        }
}

// ---------------- y12 (both branches, MFMA hi/lo): 32 atoms x 256 cols / block ----------------
__global__ __launch_bounds__(256, 2) void k_y12(const unsigned short* __restrict__ aHi,
                                                const unsigned short* __restrict__ aLo,
                                                const unsigned* __restrict__ w12h_base,
                                                const unsigned* __restrict__ w12l_base,
                                                int layer,
                                                float* __restrict__ y1,
                                                float* __restrict__ y2) {
    __shared__ __align__(16) unsigned short sH[32 * 72];
    __shared__ __align__(16) unsigned short sL[32 * 72];
    int t = threadIdx.x;
    int atom0 = blockIdx.x * 32;
    int br = atom0 >= NATOM;
    int mat = br * 3 + layer;
    const unsigned short* w12h = (const unsigned short*)(w12h_base + (size_t)mat * 8192);
    const unsigned short* w12l = (const unsigned short*)(w12l_base + (size_t)mat * 8192);
    {
        int row = t >> 3, sub = t & 7;
        *(short8*)(sH + row * 72 + sub * 8) = *(const short8*)(aHi + (size_t)(atom0 + row) * 64 + sub * 8);
        *(short8*)(sL + row * 72 + sub * 8) = *(const short8*)(aLo + (size_t)(atom0 + row) * 64 + sub * 8);
    }
    int w = t >> 6, lane = t & 63;
    int lr = lane & 15, lq = lane >> 4;

    short8 bh[2][4], bl[2][4];
#pragma unroll
    for (int kstep = 0; kstep < 2; ++kstep)
#pragma unroll
        for (int n = 0; n < 4; ++n) {
            int col = w * 64 + n * 16 + lr;
            size_t off = (size_t)col * 64 + kstep * 32 + lq * 8;
            bh[kstep][n] = *(const short8*)(w12h + off);
            bl[kstep][n] = *(const short8*)(w12l + off);
        }
    __syncthreads();

    f32x4 acc[4][2];
#pragma unroll
    for (int n = 0; n < 4; ++n)
#pragma unroll
        for (int r = 0; r < 2; ++r) acc[n][r] = f32x4{0.f, 0.f, 0.f, 0.f};

#pragma unroll
    for (int kstep = 0; kstep < 2; ++kstep) {
        int ks = kstep * 32 + lq * 8;
        short8 ah[2], al[2];
#pragma unroll
        for (int r = 0; r < 2; ++r) {
            ah[r] = *(const short8*)(sH + (r * 16 + lr) * 72 + ks);
            al[r] = *(const short8*)(sL + (r * 16 + lr) * 72 + ks);
        }
#pragma unroll
        for (int n = 0; n < 4; ++n)
#pragma unroll
            for (int r = 0; r < 2; ++r) {
                acc[n][r] = __builtin_amdgcn_mfma_f32_16x16x32_bf16(ah[r], bh[kstep][n], acc[n][r], 0, 0, 0);
                acc[n][r] = __builtin_amdgcn_mfma_f32_16x16x32_bf16(ah[r], bl[kstep][n], acc[n][r], 0, 0, 0);
                acc[n][r] = __builtin_amdgcn_mfma_f32_16x16x32_bf16(al[r], bh[kstep][n], acc[n][r], 0, 0, 0);
            }
    }

#pragma unroll
    for (int n = 0; n < 4; ++n) {
        int col = w * 64 + n * 16 + lr;
        float* dst = (col < 128) ? (y1 + col) : (y2 + col - 128);
#pragma unroll
        for (int r = 0; r < 2; ++r)
#pragma unroll
            for (int q = 0; q < 4; ++q) {
                int atom = atom0 + r * 16 + lq * 4 + q;
                dst[(size_t)atom * H] = acc[n][r][q];
            }
    }
}

// ---------------- fused conv layer (both branches) ----------------
__global__ __launch_bounds__(256, 4) void k_convfused(
        const float* __restrict__ y1,
        const float* __restrict__ y2,
        const unsigned short* __restrict__ nbrb,  // (2N*12, 48) bf16
        const int* __restrict__ idxA,
        const int* __restrict__ idxB,
        const unsigned* __restrict__ w3t,
        int layer,
        const float* __restrict__ biasA, const float* __restrict__ biasB,
        const float* __restrict__ bn1A,  const float* __restrict__ bn1B,
        const float* __restrict__ bn2A,  const float* __restrict__ bn2B,
        unsigned short* __restrict__ aHi,
        unsigned short* __restrict__ aLo) {
    __shared__ __align__(16) unsigned char pool[27072];
    float* sZ  = (float*)pool;
    float* sS1 = (float*)(pool + 25344);
    float* sH1 = sS1 + 128;
    float* sS2 = sH1 + 128;
    float* sH2 = sS2 + 64;
    int*   sJ  = (int*)(pool + 26880);

    int t = threadIdx.x;
    int atom0 = blockIdx.x * 4;              // unified 0..2N-4
    int br = atom0 >= NATOM;
    int brOff = br * NATOM;
    int R0 = atom0 * MNBR;
    const float* bias = br ? biasB : biasA;
    const float* bn1  = br ? bn1B : bn1A;
    const float* bn2  = br ? bn2B : bn2A;
    const unsigned short* w3l = (const unsigned short*)(w3t + (size_t)(br * 3 + layer) * 4096);

    // stage A: 288 data chunks (6x16B per row) + 96 zero chunks (k=48..63)
#pragma unroll
    for (int j = 0; j < 2; ++j) {
        int c = t + j * 256;
        if (c < 288) {
            int row = c / 6, sub = c - row * 6;
            short8 v = *(const short8*)(nbrb + (size_t)(R0 + row) * 48 + sub * 8);
            *(short8*)(pool + row * 144 + sub * 16) = v;
        } else if (c < 384) {
            int z = c - 288;
            int row = z >> 1, sub = 6 + (z & 1);
            *(short8*)(pool + row * 144 + sub * 16) = short8{0, 0, 0, 0, 0, 0, 0, 0};
        }
    }
    if (t < 128) {
        float g = bn1[t], be = bn1[128 + t], mu = bn1[256 + t], va = bn1[384 + t];
        float s = g * rsqrtf(va + 1e-5f);
        sS1[t] = s;
        sH1[t] = be - mu * s + bias[t] * s;
    } else if (t < 192) {
        int u = t - 128;
        float g = bn2[u], be = bn2[64 + u], mu = bn2[128 + u], va = bn2[192 + u];
        float s = g * rsqrtf(va + 1e-5f);
        sS2[u] = s;
        sH2[u] = be - mu * s;
    }
    if (t < 48) sJ[t] = ((br ? idxB : idxA) + (size_t)(atom0 - brOff) * MNBR)[t];

    int w = t >> 6, lane = t & 63;
    int lr = lane & 15, lq = lane >> 4;
    int CB = w * 32;
    short8 bfr[2][2];
#pragma unroll
    for (int kstep = 0; kstep < 2; ++kstep)
#pragma unroll
        for (int n = 0; n < 2; ++n) {
            int col = CB + n * 16 + lr;
            int ks = kstep * 32 + lq * 8;
            bfr[kstep][n] = *(const short8*)(w3l + (size_t)col * 64 + ks);
        }
    __syncthreads();

    f32x4 acc[2][3];
#pragma unroll
    for (int n = 0; n < 2; ++n)
#pragma unroll
        for (int r = 0; r < 3; ++r) acc[n][r] = f32x4{0.f, 0.f, 0.f, 0.f};

#pragma unroll
    for (int kstep = 0; kstep < 2; ++kstep) {
        int ks = kstep * 32 + lq * 8;
        short8 af[3];
#pragma unroll
        for (int r = 0; r < 3; ++r) {
            int row = r * 16 + lr;
            af[r] = *(const short8*)(pool + (size_t)row * 144 + ks * 2);
        }
#pragma unroll
        for (int n = 0; n < 2; ++n)
#pragma unroll
            for (int r = 0; r < 3; ++r)
                acc[n][r] = __builtin_amdgcn_mfma_f32_16x16x32_bf16(af[r], bfr[kstep][n], acc[n][r], 0, 0, 0);
    }
    __syncthreads();

#pragma unroll
    for (int n = 0; n < 2; ++n)
#pragma unroll
        for (int r = 0; r < 3; ++r)
#pragma unroll
            for (int q = 0; q < 4; ++q) {
                int row = r * 16 + lq * 4 + q;
                int col = CB + n * 16 + lr;
                sZ[row * 132 + col] = acc[n][r][q];
            }
    __syncthreads();

    int al = t >> 6, f = t & 63;
    int i = atom0 + al;
    float y1f = y1[(size_t)i * H + f], y1c = y1[(size_t)i * H + 64 + f];
    float s1f = sS1[f], h1f = sH1[f], s1c = sS1[64 + f], h1c = sH1[64 + f];

    int js[MNBR];
#pragma unroll
    for (int m = 0; m < MNBR; ++m) js[m] = sJ[al * MNBR + m] + brOff;
    float gf[MNBR], gc[MNBR];
#pragma unroll
    for (int m = 0; m < MNBR; ++m) {
        gf[m] = y2[(size_t)js[m] * H + f];
        gc[m] = y2[(size_t)js[m] * H + 64 + f];
    }

    float sacc = 0.f;
#pragma unroll
    for (int m = 0; m < MNBR; ++m) {
        int row = al * MNBR + m;
        float zf = sZ[row * 132 + f] + y1f + gf[m];
        float zc = sZ[row * 132 + 64 + f] + y1c + gc[m];
        zf = zf * s1f + h1f;
        zc = zc * s1c + h1c;
        sacc += sigmoidf(zf) * softplusf(zc);
    }
    size_t o = (size_t)i * F + f;
    float av = bf2f(aHi[o]) + bf2f(aLo[o]);
    float res = softplusf(av + sacc * sS2[f] + sH2[f]);
    unsigned short hh = f2bf(res);
    aHi[o] = hh;
    aLo[o] = f2bf(res - bf2f(hh));
}

// ---------------- pool (both branches) ----------------
__global__ __launch_bounds__(256) void k_pool(const unsigned short* __restrict__ aHi,
                                              const unsigned short* __restrict__ aLo,
                                              const int* __restrict__ segA,
                                              const int* __restrict__ segB,
                                              float* __restrict__ poolU,
                                              float* __restrict__ cntU) {
    int idx = blockIdx.x * 256 + threadIdx.x;  // over 2*N*F
    int n = idx >> 6, f = idx & 63;
    int br = n >= NATOM;
    int c = (br ? segB[n - NATOM] : segA[n]) + br * NCRYS;
    float v = bf2f(aHi[idx]) + bf2f(aLo[idx]);
    atomicAdd(&poolU[(size_t)c * F + f], v);
    if (f == 0) atomicAdd(&cntU[c], 1.f);
}

// ---------------- head: dense(A) + dense(B) + |diff| + FF + out ----------------
__global__ __launch_bounds__(128) void k_head(const float* __restrict__ poolU,
                                              const float* __restrict__ cntU,
                                              const float* __restrict__ denWA,
                                              const float* __restrict__ denbA,
                                              const float* __restrict__ denWB,
                                              const float* __restrict__ denbB,
                                              const float* __restrict__ ffW,
                                              const float* __restrict__ ffb,
                                              const float* __restrict__ outW,
                                              const float* __restrict__ outb,
                                              float* __restrict__ out) {
    int c = blockIdx.x;
    int h = threadIdx.x;
    __shared__ float spA[F], spB[F], sd[H], st[H];
    if (h < F) spA[h] = poolU[(size_t)c * F + h] / fmaxf(cntU[c], 1.f);
    else {
        int u = h - F;
        spB[u] = poolU[(size_t)(c + NCRYS) * F + u] / fmaxf(cntU[c + NCRYS], 1.f);
    }
    __syncthreads();
    float accA = denbA[h], accB = denbB[h];
#pragma unroll
    for (int k = 0; k < F; ++k) {
        accA = fmaf(spA[k], denWA[k * H + h], accA);
        accB = fmaf(spB[k], denWB[k * H + h], accB);
    }
    sd[h] = fabsf(softplusf(accA) - softplusf(accB));
    __syncthreads();
    float acc = ffb[h];
#pragma unroll
    for (int k = 0; k < H; ++k) acc = fmaf(sd[k], ffW[k * H + h], acc);
    st[h] = softplusf(acc) * outW[h];
    __syncthreads();
    for (int s = 64; s > 0; s >>= 1) {
        if (h < s) st[h] += st[h + s];
        __syncthreads();
    }
    if (h == 0) out[c] = st[0] + outb[0];
}

extern "C" void kernel_launch(void* const* d_in, const int* in_sizes, int n_in,
                              void* d_out, int out_size, void* d_ws, size_t ws_size,
                              hipStream_t stream) {
    const float* atomA = (const float*)d_in[0];
    const float* nbrA  = (const float*)d_in[1];
    const int*   idxA  = (const int*)d_in[2];
    const int*   segA  = (const int*)d_in[3];
    const float* embWA = (const float*)d_in[4];
    const float* embbA = (const float*)d_in[5];
    const float* convWA = (const float*)d_in[6];
    const float* convbA = (const float*)d_in[7];
    const float* bn1A  = (const float*)d_in[8];
    const float* bn2A  = (const float*)d_in[9];
    const float* denWA = (const float*)d_in[10];
    const float* denbA = (const float*)d_in[11];
    const float* atomB = (const float*)d_in[12];
    const float* nbrB  = (const float*)d_in[13];
    const int*   idxB  = (const int*)d_in[14];
    const int*   segB  = (const int*)d_in[15];
    const float* embWB = (const float*)d_in[16];
    const float* embbB = (const float*)d_in[17];
    const float* convWB = (const float*)d_in[18];
    const float* convbB = (const float*)d_in[19];
    const float* bn1B  = (const float*)d_in[20];
    const float* bn2B  = (const float*)d_in[21];
    const float* denWB = (const float*)d_in[22];
    const float* denbB = (const float*)d_in[23];
    const float* ffW   = (const float*)d_in[24];
    const float* ffb   = (const float*)d_in[25];
    const float* outW  = (const float*)d_in[26];
    const float* outb  = (const float*)d_in[27];

    float* ws = (float*)d_ws;
    float* y1    = ws;                              // 2N*H
    float* y2    = y1 + 2 * NATOM * H;              // 2N*H
    float* poolU = y2 + 2 * NATOM * H;              // 2*NCRYS*F
    float* cntU  = poolU + 2 * NCRYS * F;           // 2*NCRYS
    unsigned* w3t  = (unsigned*)(cntU + 2 * NCRYS); // 24576
    unsigned* w12h = w3t + 24576;                   // 49152
    unsigned* w12l = w12h + 49152;                  // 49152
    unsigned* embh = w12l + 49152;                  // 6144
    unsigned* embl = embh + 6144;                   // 6144
    unsigned* nbrb = embl + 6144;                   // 2N*12*24 uints (96B rows)
    unsigned short* aHi = (unsigned short*)(nbrb + (size_t)2 * NATOM * MNBR * 24);  // 2N*F
    unsigned short* aLo = aHi + 2 * NATOM * F;

    hipMemsetAsync(poolU, 0, (size_t)(2 * NCRYS * F + 2 * NCRYS) * sizeof(float), stream);
    k_wcvt<<<312, 256, 0, stream>>>(convWA, convWB, embWA, embWB, w3t, w12h, w12l, embh, embl);
    k_nbrcvt<<<2 * NATOM * MNBR * 6 / 256, 256, 0, stream>>>(nbrA, nbrB, (uint4*)nbrb);
    k_embed<<<2 * NATOM / 32, 256, 0, stream>>>(atomA, atomB, embh, embl, embbA, embbB, aHi, aLo);
    for (int l = 0; l < NCONV; ++l) {
        k_y12<<<2 * NATOM / 32, 256, 0, stream>>>(aHi, aLo, w12h, w12l, l, y1, y2);
        k_convfused<<<2 * NATOM / 4, 256, 0, stream>>>(
            y1, y2, (const unsigned short*)nbrb, idxA, idxB, w3t, l,
            convbA + l * H, convbB + l * H,
            bn1A + l * 4 * H, bn1B + l * 4 * H,
            bn2A + l * 4 * F, bn2B + l * 4 * F,
            aHi, aLo);
    }
    k_pool<<<2 * NATOM * F / 256, 256, 0, stream>>>(aHi, aLo, segA, segB, poolU, cntU);
    k_head<<<NCRYS, 128, 0, stream>>>(poolU, cntU, denWA, denbA, denWB, denbB,
                                      ffW, ffb, outW, outb, (float*)d_out);
}

// Round 10
// 249.079 us; speedup vs baseline: 2.7453x; 1.1693x over previous
//
#include <hip/hip_runtime.h>

// Paired CGCNN (separated) — R10.
// R10 vs R9: (1) y1/y2 stored as fp16 (ushort) — halves the 61.5 MB/layer
// y-traffic; error budget already dominated by bf16 nbr*W3 term. (2) k_pool
// reduces groups of 4 consecutive atoms (sorted seg) before one atomicAdd.
// Everything else identical to R9.

constexpr int NATOM = 20000;
constexpr int MNBR  = 12;
constexpr int ORIG  = 92;
constexpr int NBRF  = 41;
constexpr int F     = 64;
constexpr int H     = 128;
constexpr int NCONV = 3;
constexpr int NCRYS = 400;

#define DEVFN __device__ __forceinline__

typedef __attribute__((ext_vector_type(8))) short short8;   // 8 bf16 (4 VGPR)
typedef __attribute__((ext_vector_type(4))) float f32x4;    // MFMA acc

DEVFN float softplusf(float x) {
    return fmaxf(x, 0.f) + __logf(1.f + __expf(-fabsf(x)));
}
DEVFN float sigmoidf(float x) {
    return __builtin_amdgcn_rcpf(1.f + __expf(-x));
}
DEVFN unsigned short f2bf(float x) {  // RNE fp32->bf16
    union { float f; unsigned u; } v{x};
    unsigned r = v.u + 0x7FFF + ((v.u >> 16) & 1);
    return (unsigned short)(r >> 16);
}
DEVFN float bf2f(unsigned short h) {
    union { unsigned u; float f; } v;
    v.u = (unsigned)h << 16;
    return v.f;
}
DEVFN unsigned pk2(float a, float b) {
    return (unsigned)f2bf(a) | ((unsigned)f2bf(b) << 16);
}
DEVFN unsigned short f2h(float x) {   // fp32 -> fp16 (RNE via v_cvt)
    _Float16 h = (_Float16)x;
    union { _Float16 h; unsigned short u; } v{h};
    return v.u;
}
DEVFN float h2f(unsigned short u) {
    union { unsigned short u; _Float16 h; } v{u};
    return (float)v.h;
}

template <typename T>
DEVFN const T* upt(const T* p) {
    unsigned long long v = (unsigned long long)p;
    unsigned lo = __builtin_amdgcn_readfirstlane((unsigned)v);
    unsigned hi = __builtin_amdgcn_readfirstlane((unsigned)(v >> 32));
    return (const T*)((((unsigned long long)hi) << 32) | lo);
}

// ------- wcvt: W3^T bf16 (6x128x64) + W12^T hi/lo (6x256x64) + embW^T hi/lo (2x64x96) -------
__global__ __launch_bounds__(256) void k_wcvt(const float* __restrict__ convW_A,
                                              const float* __restrict__ convW_B,
                                              const float* __restrict__ embWA,
                                              const float* __restrict__ embWB,
                                              unsigned* __restrict__ w3t,
                                              unsigned* __restrict__ w12h,
                                              unsigned* __restrict__ w12l,
                                              unsigned* __restrict__ embh,
                                              unsigned* __restrict__ embl) {
    int e = blockIdx.x * 256 + threadIdx.x;  // 0..79871
    if (e < 24576) {
        int mat = e >> 12;
        int rem = e & 4095;
        int col = rem >> 5, kp = rem & 31, k = kp * 2;
        int br = mat / 3, l = mat - br * 3;
        const float* src = (br ? convW_B : convW_A) + (size_t)l * (2 * F + NBRF) * H + 128 * H;
        float v0 = (k < NBRF) ? src[k * H + col] : 0.f;
        float v1 = (k + 1 < NBRF) ? src[(k + 1) * H + col] : 0.f;
        w3t[e] = pk2(v0, v1);
    } else if (e < 73728) {
        int e2 = e - 24576;              // < 49152
        int mat = e2 >> 13;              // 6 mats x 8192 uints
        int rem = e2 & 8191;
        int col = rem >> 5, kp = rem & 31, k = kp * 2;
        const float* src = (mat >= 3 ? convW_B : convW_A) + (size_t)(mat % 3) * (2 * F + NBRF) * H;
        float v0, v1;
        if (col < 128) { v0 = src[k * H + col];              v1 = src[(k + 1) * H + col]; }
        else           { v0 = src[(64 + k) * H + col - 128]; v1 = src[(64 + k + 1) * H + col - 128]; }
        unsigned short h0 = f2bf(v0), h1 = f2bf(v1);
        w12h[e2] = (unsigned)h0 | ((unsigned)h1 << 16);
        w12l[e2] = (unsigned)f2bf(v0 - bf2f(h0)) | ((unsigned)f2bf(v1 - bf2f(h1)) << 16);
    } else {
        int e3 = e - 73728;              // < 6144 : embW^T, 2 br x 64 cols x 48 kp
        int br = e3 / 3072;
        int rem = e3 - br * 3072;
        int col = rem / 48, kp = rem - col * 48, k = kp * 2;
        const float* src = br ? embWB : embWA;  // (92,64)
        float v0 = (k < ORIG) ? src[k * F + col] : 0.f;
        float v1 = (k + 1 < ORIG) ? src[(k + 1) * F + col] : 0.f;
        unsigned short h0 = f2bf(v0), h1 = f2bf(v1);
        embh[e3] = (unsigned)h0 | ((unsigned)h1 << 16);
        embl[e3] = (unsigned)f2bf(v0 - bf2f(h0)) | ((unsigned)f2bf(v1 - bf2f(h1)) << 16);
    }
}

// ---------------- nbrcvt: rows (2N*12) of 41 fp32 -> 48 bf16 (96B); uint4 stores ----------------
__global__ __launch_bounds__(256) void k_nbrcvt(const float* __restrict__ nbrA,
                                                const float* __restrict__ nbrB,
                                                uint4* __restrict__ out) {
    int e = blockIdx.x * 256 + threadIdx.x;  // 0 .. 2*240000*6-1
    int row = e / 6, sub = e - row * 6;
    int br = row >= NATOM * MNBR;
    const float* s = (br ? nbrB : nbrA) + (size_t)(row - br * NATOM * MNBR) * NBRF;
    int k0 = sub * 8;
    float v[8];
#pragma unroll
    for (int j = 0; j < 8; ++j) v[j] = (k0 + j < NBRF) ? s[k0 + j] : 0.f;
    uint4 o;
    o.x = pk2(v[0], v[1]);
    o.y = pk2(v[2], v[3]);
    o.z = pk2(v[4], v[5]);
    o.w = pk2(v[6], v[7]);
    out[e] = o;
}

// ---------------- embed (MFMA hi/lo): 32 atoms x 64 cols per block ----------------
__global__ __launch_bounds__(256) void k_embed(const float* __restrict__ atomA,
                                               const float* __restrict__ atomB,
                                               const unsigned* __restrict__ embh,
                                               const unsigned* __restrict__ embl,
                                               const float* __restrict__ embbA,
                                               const float* __restrict__ embbB,
                                               unsigned short* __restrict__ aHi,
                                               unsigned short* __restrict__ aLo) {
    __shared__ __align__(16) unsigned short sH[32 * 104];  // stride 104 ushort = 208B
    __shared__ __align__(16) unsigned short sL[32 * 104];
    int t = threadIdx.x;
    int atom0 = blockIdx.x * 32;
    int br = atom0 >= NATOM;
    const float* src = (br ? atomB : atomA) + (size_t)(atom0 - br * NATOM) * ORIG;

#pragma unroll
    for (int it = 0; it < 3; ++it) {
        int idx = t + it * 256;
        if (idx < 736) {
            int row = idx / 23, sub = idx - row * 23;
            float4 v = *(const float4*)(src + (size_t)row * ORIG + sub * 4);
            int o = row * 104 + sub * 4;
            unsigned short h0 = f2bf(v.x), h1 = f2bf(v.y), h2 = f2bf(v.z), h3 = f2bf(v.w);
            *(uint2*)(sH + o) = uint2{(unsigned)h0 | ((unsigned)h1 << 16),
                                      (unsigned)h2 | ((unsigned)h3 << 16)};
            *(uint2*)(sL + o) = uint2{(unsigned)f2bf(v.x - bf2f(h0)) | ((unsigned)f2bf(v.y - bf2f(h1)) << 16),
                                      (unsigned)f2bf(v.z - bf2f(h2)) | ((unsigned)f2bf(v.w - bf2f(h3)) << 16)};
        } else if (idx < 768) {
            int row = idx - 736;
            *(uint2*)(sH + row * 104 + 92) = uint2{0, 0};
            *(uint2*)(sL + row * 104 + 92) = uint2{0, 0};
        }
    }

    int w = t >> 6, lane = t & 63;
    int lr = lane & 15, lq = lane >> 4;
    int col = w * 16 + lr;

    const unsigned short* bh_base = (const unsigned short*)embh + (size_t)br * 6144 + (size_t)col * 96;
    const unsigned short* bl_base = (const unsigned short*)embl + (size_t)br * 6144 + (size_t)col * 96;
    short8 bh[3], bl[3];
#pragma unroll
    for (int ks = 0; ks < 3; ++ks) {
        bh[ks] = *(const short8*)(bh_base + ks * 32 + lq * 8);
        bl[ks] = *(const short8*)(bl_base + ks * 32 + lq * 8);
    }
    __syncthreads();

    f32x4 acc[2];
    acc[0] = f32x4{0.f, 0.f, 0.f, 0.f};
    acc[1] = f32x4{0.f, 0.f, 0.f, 0.f};
#pragma unroll
    for (int ks = 0; ks < 3; ++ks) {
        int ko = ks * 32 + lq * 8;
        short8 ah[2], al[2];
#pragma unroll
        for (int r = 0; r < 2; ++r) {
            ah[r] = *(const short8*)(sH + (r * 16 + lr) * 104 + ko);
            al[r] = *(const short8*)(sL + (r * 16 + lr) * 104 + ko);
        }
#pragma unroll
        for (int r = 0; r < 2; ++r) {
            acc[r] = __builtin_amdgcn_mfma_f32_16x16x32_bf16(ah[r], bh[ks], acc[r], 0, 0, 0);
            acc[r] = __builtin_amdgcn_mfma_f32_16x16x32_bf16(ah[r], bl[ks], acc[r], 0, 0, 0);
            acc[r] = __builtin_amdgcn_mfma_f32_16x16x32_bf16(al[r], bh[ks], acc[r], 0, 0, 0);
        }
    }

    float bias = (br ? embbB : embbA)[col];
#pragma unroll
    for (int r = 0; r < 2; ++r)
#pragma unroll
        for (int q = 0; q < 4; ++q) {
            int atom = atom0 + r * 16 + lq * 4 + q;
            float val = acc[r][q] + bias;
            unsigned short h = f2bf(val);
            aHi[(size_t)atom * F + col] = h;
            aLo[(size_t)atom * F + col] = f2bf(val - bf2f(h));
        }
}

// ---------------- y12 (MFMA hi/lo): 32 atoms x 256 cols / block; fp16 output ----------------
__global__ __launch_bounds__(256, 2) void k_y12(const unsigned short* __restrict__ aHi,
                                                const unsigned short* __restrict__ aLo,
                                                const unsigned* __restrict__ w12h_base,
                                                const unsigned* __restrict__ w12l_base,
                                                int layer,
                                                unsigned short* __restrict__ y1,
                                                unsigned short* __restrict__ y2) {
    __shared__ __align__(16) unsigned short sH[32 * 72];
    __shared__ __align__(16) unsigned short sL[32 * 72];
    int t = threadIdx.x;
    int atom0 = blockIdx.x * 32;
    int br = atom0 >= NATOM;
    int mat = br * 3 + layer;
    const unsigned short* w12h = (const unsigned short*)(w12h_base + (size_t)mat * 8192);
    const unsigned short* w12l = (const unsigned short*)(w12l_base + (size_t)mat * 8192);
    {
        int row = t >> 3, sub = t & 7;
        *(short8*)(sH + row * 72 + sub * 8) = *(const short8*)(aHi + (size_t)(atom0 + row) * 64 + sub * 8);
        *(short8*)(sL + row * 72 + sub * 8) = *(const short8*)(aLo + (size_t)(atom0 + row) * 64 + sub * 8);
    }
    int w = t >> 6, lane = t & 63;
    int lr = lane & 15, lq = lane >> 4;

    short8 bh[2][4], bl[2][4];
#pragma unroll
    for (int kstep = 0; kstep < 2; ++kstep)
#pragma unroll
        for (int n = 0; n < 4; ++n) {
            int col = w * 64 + n * 16 + lr;
            size_t off = (size_t)col * 64 + kstep * 32 + lq * 8;
            bh[kstep][n] = *(const short8*)(w12h + off);
            bl[kstep][n] = *(const short8*)(w12l + off);
        }
    __syncthreads();

    f32x4 acc[4][2];
#pragma unroll
    for (int n = 0; n < 4; ++n)
#pragma unroll
        for (int r = 0; r < 2; ++r) acc[n][r] = f32x4{0.f, 0.f, 0.f, 0.f};

#pragma unroll
    for (int kstep = 0; kstep < 2; ++kstep) {
        int ks = kstep * 32 + lq * 8;
        short8 ah[2], al[2];
#pragma unroll
        for (int r = 0; r < 2; ++r) {
            ah[r] = *(const short8*)(sH + (r * 16 + lr) * 72 + ks);
            al[r] = *(const short8*)(sL + (r * 16 + lr) * 72 + ks);
        }
#pragma unroll
        for (int n = 0; n < 4; ++n)
#pragma unroll
            for (int r = 0; r < 2; ++r) {
                acc[n][r] = __builtin_amdgcn_mfma_f32_16x16x32_bf16(ah[r], bh[kstep][n], acc[n][r], 0, 0, 0);
                acc[n][r] = __builtin_amdgcn_mfma_f32_16x16x32_bf16(ah[r], bl[kstep][n], acc[n][r], 0, 0, 0);
                acc[n][r] = __builtin_amdgcn_mfma_f32_16x16x32_bf16(al[r], bh[kstep][n], acc[n][r], 0, 0, 0);
            }
    }

#pragma unroll
    for (int n = 0; n < 4; ++n) {
        int col = w * 64 + n * 16 + lr;
        unsigned short* dst = (col < 128) ? (y1 + col) : (y2 + col - 128);
#pragma unroll
        for (int r = 0; r < 2; ++r)
#pragma unroll
            for (int q = 0; q < 4; ++q) {
                int atom = atom0 + r * 16 + lq * 4 + q;
                dst[(size_t)atom * H] = f2h(acc[n][r][q]);
            }
    }
}

// ---------------- fused conv layer (both branches); fp16 y inputs ----------------
__global__ __launch_bounds__(256, 4) void k_convfused(
        const unsigned short* __restrict__ y1,
        const unsigned short* __restrict__ y2,
        const unsigned short* __restrict__ nbrb,  // (2N*12, 48) bf16
        const int* __restrict__ idxA,
        const int* __restrict__ idxB,
        const unsigned* __restrict__ w3t,
        int layer,
        const float* __restrict__ biasA, const float* __restrict__ biasB,
        const float* __restrict__ bn1A,  const float* __restrict__ bn1B,
        const float* __restrict__ bn2A,  const float* __restrict__ bn2B,
        unsigned short* __restrict__ aHi,
        unsigned short* __restrict__ aLo) {
    __shared__ __align__(16) unsigned char pool[27072];
    float* sZ  = (float*)pool;
    float* sS1 = (float*)(pool + 25344);
    float* sH1 = sS1 + 128;
    float* sS2 = sH1 + 128;
    float* sH2 = sS2 + 64;
    int*   sJ  = (int*)(pool + 26880);

    int t = threadIdx.x;
    int atom0 = blockIdx.x * 4;              // unified 0..2N-4
    int br = atom0 >= NATOM;
    int brOff = br * NATOM;
    int R0 = atom0 * MNBR;
    const float* bias = br ? biasB : biasA;
    const float* bn1  = br ? bn1B : bn1A;
    const float* bn2  = br ? bn2B : bn2A;
    const unsigned short* w3l = (const unsigned short*)(w3t + (size_t)(br * 3 + layer) * 4096);

    // stage A: 288 data chunks (6x16B per row) + 96 zero chunks (k=48..63)
#pragma unroll
    for (int j = 0; j < 2; ++j) {
        int c = t + j * 256;
        if (c < 288) {
            int row = c / 6, sub = c - row * 6;
            short8 v = *(const short8*)(nbrb + (size_t)(R0 + row) * 48 + sub * 8);
            *(short8*)(pool + row * 144 + sub * 16) = v;
        } else if (c < 384) {
            int z = c - 288;
            int row = z >> 1, sub = 6 + (z & 1);
            *(short8*)(pool + row * 144 + sub * 16) = short8{0, 0, 0, 0, 0, 0, 0, 0};
        }
    }
    if (t < 128) {
        float g = bn1[t], be = bn1[128 + t], mu = bn1[256 + t], va = bn1[384 + t];
        float s = g * rsqrtf(va + 1e-5f);
        sS1[t] = s;
        sH1[t] = be - mu * s + bias[t] * s;
    } else if (t < 192) {
        int u = t - 128;
        float g = bn2[u], be = bn2[64 + u], mu = bn2[128 + u], va = bn2[192 + u];
        float s = g * rsqrtf(va + 1e-5f);
        sS2[u] = s;
        sH2[u] = be - mu * s;
    }
    if (t < 48) sJ[t] = ((br ? idxB : idxA) + (size_t)(atom0 - brOff) * MNBR)[t];

    int w = t >> 6, lane = t & 63;
    int lr = lane & 15, lq = lane >> 4;
    int CB = w * 32;
    short8 bfr[2][2];
#pragma unroll
    for (int kstep = 0; kstep < 2; ++kstep)
#pragma unroll
        for (int n = 0; n < 2; ++n) {
            int col = CB + n * 16 + lr;
            int ks = kstep * 32 + lq * 8;
            bfr[kstep][n] = *(const short8*)(w3l + (size_t)col * 64 + ks);
        }
    __syncthreads();

    f32x4 acc[2][3];
#pragma unroll
    for (int n = 0; n < 2; ++n)
#pragma unroll
        for (int r = 0; r < 3; ++r) acc[n][r] = f32x4{0.f, 0.f, 0.f, 0.f};

#pragma unroll
    for (int kstep = 0; kstep < 2; ++kstep) {
        int ks = kstep * 32 + lq * 8;
        short8 af[3];
#pragma unroll
        for (int r = 0; r < 3; ++r) {
            int row = r * 16 + lr;
            af[r] = *(const short8*)(pool + (size_t)row * 144 + ks * 2);
        }
#pragma unroll
        for (int n = 0; n < 2; ++n)
#pragma unroll
            for (int r = 0; r < 3; ++r)
                acc[n][r] = __builtin_amdgcn_mfma_f32_16x16x32_bf16(af[r], bfr[kstep][n], acc[n][r], 0, 0, 0);
    }
    __syncthreads();

#pragma unroll
    for (int n = 0; n < 2; ++n)
#pragma unroll
        for (int r = 0; r < 3; ++r)
#pragma unroll
            for (int q = 0; q < 4; ++q) {
                int row = r * 16 + lq * 4 + q;
                int col = CB + n * 16 + lr;
                sZ[row * 132 + col] = acc[n][r][q];
            }
    __syncthreads();

    int al = t >> 6, f = t & 63;
    int i = atom0 + al;
    float y1f = h2f(y1[(size_t)i * H + f]), y1c = h2f(y1[(size_t)i * H + 64 + f]);
    float s1f = sS1[f], h1f = sH1[f], s1c = sS1[64 + f], h1c = sH1[64 + f];

    int js[MNBR];
#pragma unroll
    for (int m = 0; m < MNBR; ++m) js[m] = sJ[al * MNBR + m] + brOff;
    float gf[MNBR], gc[MNBR];
#pragma unroll
    for (int m = 0; m < MNBR; ++m) {
        gf[m] = h2f(y2[(size_t)js[m] * H + f]);
        gc[m] = h2f(y2[(size_t)js[m] * H + 64 + f]);
    }

    float sacc = 0.f;
#pragma unroll
    for (int m = 0; m < MNBR; ++m) {
        int row = al * MNBR + m;
        float zf = sZ[row * 132 + f] + y1f + gf[m];
        float zc = sZ[row * 132 + 64 + f] + y1c + gc[m];
        zf = zf * s1f + h1f;
        zc = zc * s1c + h1c;
        sacc += sigmoidf(zf) * softplusf(zc);
    }
    size_t o = (size_t)i * F + f;
    float av = bf2f(aHi[o]) + bf2f(aLo[o]);
    float res = softplusf(av + sacc * sS2[f] + sH2[f]);
    unsigned short hh = f2bf(res);
    aHi[o] = hh;
    aLo[o] = f2bf(res - bf2f(hh));
}

// ---------------- pool: 4-atom groups (sorted seg -> mostly 1 atomic per 4) ----------------
__global__ __launch_bounds__(256) void k_pool(const unsigned short* __restrict__ aHi,
                                              const unsigned short* __restrict__ aLo,
                                              const int* __restrict__ segA,
                                              const int* __restrict__ segB,
                                              float* __restrict__ poolU,
                                              float* __restrict__ cntU) {
    int t = threadIdx.x;
    int f = t & 63, g = t >> 6;
    int n0 = blockIdx.x * 16 + g * 4;        // 4 atoms per thread-group
    int br = n0 >= NATOM;                    // 16-atom blocks never straddle (N%16==0)
    const int* seg = br ? segB : segA;
    int nl = n0 - br * NATOM;
    int s0 = seg[nl], s1 = seg[nl + 1], s2 = seg[nl + 2], s3 = seg[nl + 3];
    float v0 = bf2f(aHi[(size_t)(n0 + 0) * F + f]) + bf2f(aLo[(size_t)(n0 + 0) * F + f]);
    float v1 = bf2f(aHi[(size_t)(n0 + 1) * F + f]) + bf2f(aLo[(size_t)(n0 + 1) * F + f]);
    float v2 = bf2f(aHi[(size_t)(n0 + 2) * F + f]) + bf2f(aLo[(size_t)(n0 + 2) * F + f]);
    float v3 = bf2f(aHi[(size_t)(n0 + 3) * F + f]) + bf2f(aLo[(size_t)(n0 + 3) * F + f]);
    int cOff = br * NCRYS;
    if (s0 == s3) {  // sorted => s0==s1==s2==s3
        atomicAdd(&poolU[(size_t)(s0 + cOff) * F + f], v0 + v1 + v2 + v3);
        if (f == 0) atomicAdd(&cntU[s0 + cOff], 4.f);
    } else {
        atomicAdd(&poolU[(size_t)(s0 + cOff) * F + f], v0);
        atomicAdd(&poolU[(size_t)(s1 + cOff) * F + f], v1);
        atomicAdd(&poolU[(size_t)(s2 + cOff) * F + f], v2);
        atomicAdd(&poolU[(size_t)(s3 + cOff) * F + f], v3);
        if (f == 0) {
            atomicAdd(&cntU[s0 + cOff], 1.f);
            atomicAdd(&cntU[s1 + cOff], 1.f);
            atomicAdd(&cntU[s2 + cOff], 1.f);
            atomicAdd(&cntU[s3 + cOff], 1.f);
        }
    }
}

// ---------------- head: dense(A) + dense(B) + |diff| + FF + out ----------------
__global__ __launch_bounds__(128) void k_head(const float* __restrict__ poolU,
                                              const float* __restrict__ cntU,
                                              const float* __restrict__ denWA,
                                              const float* __restrict__ denbA,
                                              const float* __restrict__ denWB,
                                              const float* __restrict__ denbB,
                                              const float* __restrict__ ffW,
                                              const float* __restrict__ ffb,
                                              const float* __restrict__ outW,
                                              const float* __restrict__ outb,
                                              float* __restrict__ out) {
    int c = blockIdx.x;
    int h = threadIdx.x;
    __shared__ float spA[F], spB[F], sd[H], st[H];
    if (h < F) spA[h] = poolU[(size_t)c * F + h] / fmaxf(cntU[c], 1.f);
    else {
        int u = h - F;
        spB[u] = poolU[(size_t)(c + NCRYS) * F + u] / fmaxf(cntU[c + NCRYS], 1.f);
    }
    __syncthreads();
    float accA = denbA[h], accB = denbB[h];
#pragma unroll
    for (int k = 0; k < F; ++k) {
        accA = fmaf(spA[k], denWA[k * H + h], accA);
        accB = fmaf(spB[k], denWB[k * H + h], accB);
    }
    sd[h] = fabsf(softplusf(accA) - softplusf(accB));
    __syncthreads();
    float acc = ffb[h];
#pragma unroll
    for (int k = 0; k < H; ++k) acc = fmaf(sd[k], ffW[k * H + h], acc);
    st[h] = softplusf(acc) * outW[h];
    __syncthreads();
    for (int s = 64; s > 0; s >>= 1) {
        if (h < s) st[h] += st[h + s];
        __syncthreads();
    }
    if (h == 0) out[c] = st[0] + outb[0];
}

extern "C" void kernel_launch(void* const* d_in, const int* in_sizes, int n_in,
                              void* d_out, int out_size, void* d_ws, size_t ws_size,
                              hipStream_t stream) {
    const float* atomA = (const float*)d_in[0];
    const float* nbrA  = (const float*)d_in[1];
    const int*   idxA  = (const int*)d_in[2];
    const int*   segA  = (const int*)d_in[3];
    const float* embWA = (const float*)d_in[4];
    const float* embbA = (const float*)d_in[5];
    const float* convWA = (const float*)d_in[6];
    const float* convbA = (const float*)d_in[7];
    const float* bn1A  = (const float*)d_in[8];
    const float* bn2A  = (const float*)d_in[9];
    const float* denWA = (const float*)d_in[10];
    const float* denbA = (const float*)d_in[11];
    const float* atomB = (const float*)d_in[12];
    const float* nbrB  = (const float*)d_in[13];
    const int*   idxB  = (const int*)d_in[14];
    const int*   segB  = (const int*)d_in[15];
    const float* embWB = (const float*)d_in[16];
    const float* embbB = (const float*)d_in[17];
    const float* convWB = (const float*)d_in[18];
    const float* convbB = (const float*)d_in[19];
    const float* bn1B  = (const float*)d_in[20];
    const float* bn2B  = (const float*)d_in[21];
    const float* denWB = (const float*)d_in[22];
    const float* denbB = (const float*)d_in[23];
    const float* ffW   = (const float*)d_in[24];
    const float* ffb   = (const float*)d_in[25];
    const float* outW  = (const float*)d_in[26];
    const float* outb  = (const float*)d_in[27];

    unsigned short* y1 = (unsigned short*)d_ws;         // 2N*H fp16
    unsigned short* y2 = y1 + (size_t)2 * NATOM * H;    // 2N*H fp16
    float* poolU = (float*)(y2 + (size_t)2 * NATOM * H);  // 2*NCRYS*F
    float* cntU  = poolU + 2 * NCRYS * F;               // 2*NCRYS
    unsigned* w3t  = (unsigned*)(cntU + 2 * NCRYS);     // 24576
    unsigned* w12h = w3t + 24576;                       // 49152
    unsigned* w12l = w12h + 49152;                      // 49152
    unsigned* embh = w12l + 49152;                      // 6144
    unsigned* embl = embh + 6144;                       // 6144
    unsigned* nbrb = embl + 6144;                       // 2N*12*24 uints (96B rows)
    unsigned short* aHi = (unsigned short*)(nbrb + (size_t)2 * NATOM * MNBR * 24);  // 2N*F
    unsigned short* aLo = aHi + 2 * NATOM * F;

    hipMemsetAsync(poolU, 0, (size_t)(2 * NCRYS * F + 2 * NCRYS) * sizeof(float), stream);
    k_wcvt<<<312, 256, 0, stream>>>(convWA, convWB, embWA, embWB, w3t, w12h, w12l, embh, embl);
    k_nbrcvt<<<2 * NATOM * MNBR * 6 / 256, 256, 0, stream>>>(nbrA, nbrB, (uint4*)nbrb);
    k_embed<<<2 * NATOM / 32, 256, 0, stream>>>(atomA, atomB, embh, embl, embbA, embbB, aHi, aLo);
    for (int l = 0; l < NCONV; ++l) {
        k_y12<<<2 * NATOM / 32, 256, 0, stream>>>(aHi, aLo, w12h, w12l, l, y1, y2);
        k_convfused<<<2 * NATOM / 4, 256, 0, stream>>>(
            y1, y2, (const unsigned short*)nbrb, idxA, idxB, w3t, l,
            convbA + l * H, convbB + l * H,
            bn1A + l * 4 * H, bn1B + l * 4 * H,
            bn2A + l * 4 * F, bn2B + l * 4 * F,
            aHi, aLo);
    }
    k_pool<<<2 * NATOM * F / (256 * 4), 256, 0, stream>>>(aHi, aLo, segA, segB, poolU, cntU);
    k_head<<<NCRYS, 128, 0, stream>>>(poolU, cntU, denWA, denbA, denWB, denbB,
                                      ffW, ffb, outW, outb, (float*)d_out);
}